// Round 1
// baseline (392.073 us; speedup 1.0000x reference)
//
#include <hip/hip_runtime.h>

#define NB 128
#define NS 256
#define ND 256
#define NH 8
#define NHD 2048
static constexpr float EPS = 1e-5f;

// ---------- helpers ----------
__device__ __forceinline__ float block_reduce_sum(float v, float* red, int t) {
  __syncthreads();              // protect previous user of red
  red[t] = v;
  __syncthreads();
  for (int off = 128; off > 0; off >>= 1) {
    if (t < off) red[t] += red[t + off];
    __syncthreads();
  }
  return red[0];
}

// ---------- K0: per-matrix meta: wbar (col-mean of rows), l = 2/HD * W.b, bbar, mean(b^2)
// meta layout: [0..255]=wbar, [256..511]=l, [512]=bbar, [513]=mean(b^2)
__global__ __launch_bounds__(256) void k_meta(const float* __restrict__ Wk,
                                              const float* __restrict__ bk,
                                              const float* __restrict__ Wv,
                                              const float* __restrict__ bv,
                                              float* __restrict__ kmeta,
                                              float* __restrict__ vmeta) {
  int sel = blockIdx.y, c = blockIdx.x, t = threadIdx.x;
  const float* W = sel ? Wv : Wk;
  const float* bvec = sel ? bv : bk;
  float* meta = sel ? vmeta : kmeta;
  __shared__ float red[256];
  float s_w = 0.f, s_l = 0.f;
  const float* row = W + (size_t)c * NHD;
  for (int j = t; j < NHD; j += 256) { float w = row[j]; s_w += w; s_l += w * bvec[j]; }
  s_w = block_reduce_sum(s_w, red, t);
  s_l = block_reduce_sum(s_l, red, t);
  if (t == 0) { meta[c] = s_w * (1.0f / NHD); meta[256 + c] = s_l * (2.0f / NHD); }
  if (c == 0) {
    float s_b = 0.f, s_b2 = 0.f;
    for (int j = t; j < NHD; j += 256) { float bb = bvec[j]; s_b += bb; s_b2 += bb * bb; }
    s_b = block_reduce_sum(s_b, red, t);
    s_b2 = block_reduce_sum(s_b2, red, t);
    if (t == 0) { meta[512] = s_b * (1.0f / NHD); meta[513] = s_b2 * (1.0f / NHD); }
  }
}

// ---------- K2a: partial A*A^T over K-slices (grid 8x8x8: z = ks*2+sel)
__global__ __launch_bounds__(256) void k_aat(const float* __restrict__ Wk,
                                             const float* __restrict__ Wv,
                                             float* __restrict__ MkP,
                                             float* __restrict__ MvP) {
  int bi = blockIdx.x, bj = blockIdx.y;
  int sel = blockIdx.z & 1, ks = blockIdx.z >> 1;
  const float* A = sel ? Wv : Wk;
  float* outP = (sel ? MvP : MkP) + ks * (256 * 256);
  int t = threadIdx.x;
  __shared__ float As[32][129];
  __shared__ float Bs[32][129];
  int ty = t >> 4, tx = t & 15;
  float a00 = 0.f, a01 = 0.f, a10 = 0.f, a11 = 0.f;
  for (int kc = 0; kc < 4; ++kc) {
    int k0 = ks * 512 + kc * 128;
    __syncthreads();
    for (int i = 0; i < 16; ++i) {
      int li = t + 256 * i;
      int r = li >> 7, cc = li & 127;
      As[r][cc] = A[(size_t)(bi * 32 + r) * NHD + k0 + cc];
      Bs[r][cc] = A[(size_t)(bj * 32 + r) * NHD + k0 + cc];
    }
    __syncthreads();
    for (int k = 0; k < 128; ++k) {
      float x0 = As[ty][k], x1 = As[ty + 16][k];
      float y0 = Bs[tx][k], y1 = Bs[tx + 16][k];
      a00 = fmaf(x0, y0, a00); a01 = fmaf(x0, y1, a01);
      a10 = fmaf(x1, y0, a10); a11 = fmaf(x1, y1, a11);
    }
  }
  int r0 = bi * 32 + ty, c0 = bj * 32 + tx;
  outP[r0 * 256 + c0] = a00;
  outP[r0 * 256 + c0 + 16] = a01;
  outP[(r0 + 16) * 256 + c0] = a10;
  outP[(r0 + 16) * 256 + c0 + 16] = a11;
}

__global__ __launch_bounds__(256) void k_aat_reduce(const float* __restrict__ MkP,
                                                    const float* __restrict__ MvP,
                                                    float* __restrict__ Mk,
                                                    float* __restrict__ Mv) {
  int sel = blockIdx.y;
  const float* P = sel ? MvP : MkP;
  float* O = sel ? Mv : Mk;
  int idx = blockIdx.x * 256 + threadIdx.x;
  O[idx] = (P[idx] + P[65536 + idx] + P[131072 + idx] + P[196608 + idx]) * (1.0f / NHD);
}

// ---------- K3: q = LN(local @ Wq + bq) -> q_ln [B, HD]
__global__ __launch_bounds__(256) void k_qln(const float* __restrict__ local,
                                             const float* __restrict__ Wq,
                                             const float* __restrict__ bq,
                                             const float* __restrict__ gq,
                                             const float* __restrict__ betq,
                                             float* __restrict__ q_ln) {
  int b = blockIdx.x, t = threadIdx.x;
  __shared__ float ls[256];
  __shared__ float red[256];
  ls[t] = local[b * ND + t];
  __syncthreads();
  float acc[8];
#pragma unroll
  for (int r = 0; r < 8; ++r) acc[r] = bq[r * 256 + t];
  for (int c = 0; c < ND; ++c) {
    float lv = ls[c];
    const float* wrow = Wq + (size_t)c * NHD + t;
#pragma unroll
    for (int r = 0; r < 8; ++r) acc[r] = fmaf(lv, wrow[r * 256], acc[r]);
  }
  float s1 = 0.f, s2 = 0.f;
#pragma unroll
  for (int r = 0; r < 8; ++r) { s1 += acc[r]; s2 += acc[r] * acc[r]; }
  s1 = block_reduce_sum(s1, red, t);
  s2 = block_reduce_sum(s2, red, t);
  float m = s1 * (1.0f / NHD);
  float var = s2 * (1.0f / NHD) - m * m;
  float is = 1.0f / sqrtf(var + EPS);
#pragma unroll
  for (int r = 0; r < 8; ++r) {
    int j = r * 256 + t;
    q_ln[(size_t)b * NHD + j] = (acc[r] - m) * is * gq[j] + betq[j];
  }
}

// ---------- K4: wkeff[b,h,c] = sum_d Wk[c, h*256+d] * q[b,hd]*gk ; plus cb,G,T per (b,h)
__global__ __launch_bounds__(256) void k_wkeff(const float* __restrict__ q_ln,
                                               const float* __restrict__ Wk,
                                               const float* __restrict__ bk,
                                               const float* __restrict__ gk,
                                               const float* __restrict__ betk,
                                               float* __restrict__ wkeff,
                                               float* __restrict__ cbGT) {
  int h = blockIdx.x, b = blockIdx.y, t = threadIdx.x;
  __shared__ float qg[256];
  __shared__ float red[256];
  int j = h * 256 + t;
  float q = q_ln[(size_t)b * NHD + j];
  float qgv = q * gk[j];
  qg[t] = qgv;
  float cb = block_reduce_sum(bk[j] * qgv, red, t);
  float G = block_reduce_sum(qgv, red, t);
  float T = block_reduce_sum(q * betk[j], red, t);
  float acc = 0.f;
  const float4* wr = (const float4*)(Wk + (size_t)t * NHD + h * 256);
#pragma unroll 4
  for (int d4 = 0; d4 < 64; ++d4) {
    float4 w = wr[d4];
    acc += w.x * qg[d4 * 4] + w.y * qg[d4 * 4 + 1] + w.z * qg[d4 * 4 + 2] + w.w * qg[d4 * 4 + 3];
  }
  wkeff[(size_t)(b * NH + h) * ND + t] = acc;
  if (t == 0) { float* p = cbGT + (b * NH + h) * 4; p[0] = cb; p[1] = G; p[2] = T; }
}

// ---------- K5a: per-row LN moments via quadratic form  y = x^T M x + x.l + c ; m = x.wbar + bbar
__global__ __launch_bounds__(256, 2) void k_moments(const float* __restrict__ dist,
                                                    const float* __restrict__ sites,
                                                    const float* __restrict__ Mk,
                                                    const float* __restrict__ Mv,
                                                    const float* __restrict__ kmeta,
                                                    const float* __restrict__ vmeta,
                                                    float* __restrict__ mk_arr,
                                                    float* __restrict__ sk_arr,
                                                    float* __restrict__ mv_arr,
                                                    float* __restrict__ sv_arr) {
  int sel = blockIdx.y;
  const float* X = sel ? sites : dist;
  const float* M = sel ? Mv : Mk;
  const float* meta = sel ? vmeta : kmeta;
  float* m_out = sel ? mv_arr : mk_arr;
  float* s_out = sel ? sv_arr : sk_arr;
  int t = threadIdx.x;
  int row0 = blockIdx.x * 32;
  __shared__ float Xs[32][257];
  __shared__ float Mt[32][260];
  __shared__ float redA[16][17];
  __shared__ float redB[16][17];
  __shared__ float redM[32][9];
  __shared__ float redL[32][9];
  __shared__ float yrow[32];

  const float* Xbase = X + (size_t)row0 * 256;
  for (int i = 0; i < 32; ++i) {
    int li = t + 256 * i;
    Xs[li >> 8][li & 255] = Xbase[li];
  }
  int sub = t >> 4, rr = t & 15;
  float t0[16], t1[16];
#pragma unroll
  for (int i = 0; i < 16; ++i) { t0[i] = 0.f; t1[i] = 0.f; }

  for (int ct = 0; ct < 8; ++ct) {
    __syncthreads();
    for (int i = 0; i < 32; ++i) {
      int li = t + 256 * i;
      Mt[li >> 8][li & 255] = M[ct * 32 * 256 + li];
    }
    __syncthreads();
    for (int cc = 0; cc < 32; ++cc) {
      float x0 = Xs[rr][ct * 32 + cc];
      float x1 = Xs[rr + 16][ct * 32 + cc];
      const float* mr = &Mt[cc][sub * 16];
#pragma unroll
      for (int i = 0; i < 16; ++i) {
        float mvv = mr[i];
        t0[i] = fmaf(x0, mvv, t0[i]);
        t1[i] = fmaf(x1, mvv, t1[i]);
      }
    }
  }
  // y partials
  float y0 = 0.f, y1v = 0.f;
#pragma unroll
  for (int i = 0; i < 16; ++i) {
    y0 = fmaf(Xs[rr][sub * 16 + i], t0[i], y0);
    y1v = fmaf(Xs[rr + 16][sub * 16 + i], t1[i], y1v);
  }
  redA[rr][sub] = y0;
  redB[rr][sub] = y1v;
  // mean / linear-term partials: thread -> (row=t>>3, seg=t&7)
  int mrow = t >> 3, seg = t & 7;
  float pm = 0.f, pl = 0.f;
  for (int c = seg * 32; c < seg * 32 + 32; ++c) {
    float x = Xs[mrow][c];
    pm = fmaf(x, meta[c], pm);
    pl = fmaf(x, meta[256 + c], pl);
  }
  redM[mrow][seg] = pm;
  redL[mrow][seg] = pl;
  __syncthreads();
  if (t < 32) {
    float yq = 0.f;
    if (t < 16) { for (int i = 0; i < 16; ++i) yq += redA[t][i]; }
    else        { for (int i = 0; i < 16; ++i) yq += redB[t - 16][i]; }
    float sm = 0.f, sl = 0.f;
    for (int i = 0; i < 8; ++i) { sm += redM[t][i]; sl += redL[t][i]; }
    float mk = sm + meta[512];
    float lin = sl + meta[513];
    float var = fmaxf(yq + lin - mk * mk, 0.0f) + EPS;
    m_out[row0 + t] = mk;
    s_out[row0 + t] = 1.0f / sqrtf(var);
  }
}

// ---------- K5: attention scores + softmax + weighted site accumulation
__global__ __launch_bounds__(256, 1) void k_attn(const float* __restrict__ dist,
                                                 const float* __restrict__ sites,
                                                 const int* __restrict__ mask_i,
                                                 const float* __restrict__ wkeff,
                                                 const float* __restrict__ cbGT,
                                                 const float* __restrict__ mk_arr,
                                                 const float* __restrict__ sk_arr,
                                                 const float* __restrict__ mv_arr,
                                                 const float* __restrict__ sv_arr,
                                                 float* __restrict__ zbuf,
                                                 float* __restrict__ bg) {
  int b = blockIdx.x, t = threadIdx.x;
  __shared__ float Xs[64][257];
  __shared__ float wks[8][256];
  __shared__ float us[8][260];
  __shared__ float cbs[8], Gs[8], Ts[8];
  __shared__ int maskmode;

  // detect mask storage: int32 {0,1} vs packed bytes. First 8192 ints are
  // in-bounds under both layouts; any value >1 => byte layout.
  int anyv = 0;
  for (int i = t; i < 8192; i += 256) {
    unsigned v = (unsigned)mask_i[i];
    if (v > 1u) anyv = 1;
  }
  if (t == 0) maskmode = 0;
  __syncthreads();
  if (anyv) maskmode = 1;
  for (int i = 0; i < 8; ++i) wks[i][t] = wkeff[(size_t)(b * NH + i) * ND + t];
  if (t < 8) {
    const float* p = cbGT + (b * NH + t) * 4;
    cbs[t] = p[0]; Gs[t] = p[1]; Ts[t] = p[2];
  }
  __syncthreads();
  const int mbytes = maskmode;
  const unsigned char* mask_b = (const unsigned char*)mask_i;
  int hg = t >> 6, sl = t & 63;

  for (int chunk = 0; chunk < 4; ++chunk) {
    const float* Xb = dist + ((size_t)b * NS + chunk * 64) * ND;
    for (int i = 0; i < 64; ++i) {
      int li = t + 256 * i;
      Xs[li >> 8][li & 255] = Xb[li];
    }
    __syncthreads();
    int s = chunk * 64 + sl;
    float mks = mk_arr[b * NS + s], sks = sk_arr[b * NS + s];
    int mbit = mbytes ? (int)mask_b[b * NS + s] : mask_i[b * NS + s];
    float d0 = 0.f, d1 = 0.f;
#pragma unroll 4
    for (int c = 0; c < 256; ++c) {
      float x = Xs[sl][c];
      d0 = fmaf(x, wks[hg][c], d0);
      d1 = fmaf(x, wks[hg + 4][c], d1);
    }
    float u0 = ((d0 + cbs[hg] - mks * Gs[hg]) * sks + Ts[hg]) * 0.0625f;
    float u1 = ((d1 + cbs[hg + 4] - mks * Gs[hg + 4]) * sks + Ts[hg + 4]) * 0.0625f;
    if (mbit) { u0 = -1e30f; u1 = -1e30f; }
    us[hg][s] = u0;
    us[hg + 4][s] = u1;
    __syncthreads();
  }

  // softmax per head row + fold in 1/sigma_v; accumulate beta,gamma
  int hq = t >> 5, ln = t & 31;
  float vals[8];
  float mx = -3.0e38f;
#pragma unroll
  for (int i = 0; i < 8; ++i) { vals[i] = us[hq][ln + 32 * i]; mx = fmaxf(mx, vals[i]); }
  for (int off = 16; off > 0; off >>= 1) mx = fmaxf(mx, __shfl_xor(mx, off, 32));
  float sum = 0.f;
#pragma unroll
  for (int i = 0; i < 8; ++i) { vals[i] = expf(vals[i] - mx); sum += vals[i]; }
  for (int off = 16; off > 0; off >>= 1) sum += __shfl_xor(sum, off, 32);
  float inv = 1.0f / sum;
  float bpart = 0.f, gpart = 0.f;
#pragma unroll
  for (int i = 0; i < 8; ++i) {
    int s = ln + 32 * i;
    float a = vals[i] * inv;
    float sv = sv_arr[b * NS + s];
    float mv = mv_arr[b * NS + s];
    float w = a * sv;
    us[hq][s] = w;  // overwrite scores with attn/sigma_v
    bpart += w;
    gpart += w * mv;
  }
  for (int off = 16; off > 0; off >>= 1) {
    bpart += __shfl_xor(bpart, off, 32);
    gpart += __shfl_xor(gpart, off, 32);
  }
  if (ln == 0) { float* p = bg + (b * NH + hq) * 2; p[0] = bpart; p[1] = gpart; }

  // z[h,c] = sum_s w[h,s] * sites[b,s,c]
  float accz[8];
#pragma unroll
  for (int i = 0; i < 8; ++i) accz[i] = 0.f;
  for (int chunk = 0; chunk < 4; ++chunk) {
    __syncthreads();
    const float* Xb = sites + ((size_t)b * NS + chunk * 64) * ND;
    for (int i = 0; i < 64; ++i) {
      int li = t + 256 * i;
      Xs[li >> 8][li & 255] = Xb[li];
    }
    __syncthreads();
    for (int s0 = 0; s0 < 64; ++s0) {
      float x = Xs[s0][t];
      int s = chunk * 64 + s0;
#pragma unroll
      for (int hh = 0; hh < 8; ++hh) accz[hh] = fmaf(us[hh][s], x, accz[hh]);
    }
  }
#pragma unroll
  for (int hh = 0; hh < 8; ++hh) zbuf[(size_t)(b * NH + hh) * ND + t] = accz[hh];
}

// ---------- K6: attnV via z@Wv, residual, LN1, @Wo, LN2 ; also write constant 'a' output
__global__ __launch_bounds__(256) void k_out(const float* __restrict__ zbuf,
                                             const float* __restrict__ bg,
                                             const float* __restrict__ q_ln,
                                             const float* __restrict__ Wv,
                                             const float* __restrict__ bv,
                                             const float* __restrict__ gv,
                                             const float* __restrict__ betv,
                                             const float* __restrict__ g1,
                                             const float* __restrict__ b1,
                                             const float* __restrict__ Wo,
                                             const float* __restrict__ bo,
                                             const float* __restrict__ g2,
                                             const float* __restrict__ b2,
                                             const float* __restrict__ beta_a,
                                             float* __restrict__ out) {
  int b = blockIdx.x, t = threadIdx.x;
  __shared__ float zs[8][257];
  __shared__ float y1s[2048];
  __shared__ float red[256];
  __shared__ float bets[8], gams[8];
  for (int i = 0; i < 8; ++i) zs[i][t] = zbuf[(size_t)(b * NH + i) * ND + t];
  if (t < 8) { const float* p = bg + (b * NH + t) * 2; bets[t] = p[0]; gams[t] = p[1]; }
  __syncthreads();
  float acc[8];
#pragma unroll
  for (int r = 0; r < 8; ++r) acc[r] = 0.f;
  for (int c = 0; c < 256; ++c) {
    const float* wrow = Wv + (size_t)c * NHD + t;
#pragma unroll
    for (int r = 0; r < 8; ++r) acc[r] = fmaf(zs[r][c], wrow[r * 256], acc[r]);
  }
  float s1 = 0.f, s2 = 0.f;
  float vv[8];
#pragma unroll
  for (int r = 0; r < 8; ++r) {
    int j = r * 256 + t;
    float av = gv[j] * (acc[r] + bv[j] * bets[r] - gams[r]) + betv[j];
    float o = av + q_ln[(size_t)b * NHD + j];
    vv[r] = o;
    s1 += o;
    s2 += o * o;
  }
  s1 = block_reduce_sum(s1, red, t);
  s2 = block_reduce_sum(s2, red, t);
  float m = s1 * (1.0f / NHD);
  float var = s2 * (1.0f / NHD) - m * m;
  float is = 1.0f / sqrtf(var + EPS);
#pragma unroll
  for (int r = 0; r < 8; ++r) {
    int j = r * 256 + t;
    y1s[j] = (vv[r] - m) * is * g1[j] + b1[j];
  }
  __syncthreads();
  float acc2 = bo[t];
  for (int jj = 0; jj < 2048; ++jj) acc2 = fmaf(y1s[jj], Wo[(size_t)jj * 256 + t], acc2);
  float q1 = block_reduce_sum(acc2, red, t);
  float q2 = block_reduce_sum(acc2 * acc2, red, t);
  float m2 = q1 * (1.0f / 256.0f);
  float v2 = q2 * (1.0f / 256.0f) - m2 * m2;
  float is2 = 1.0f / sqrtf(v2 + EPS);
  out[NB * NS + b * 256 + t] = (acc2 - m2) * is2 * g2[t] + b2[t];
  // output 0: a == beta_a (LayerNorm over a size-1 axis)
  out[b * 256 + t] = beta_a[0];
}

extern "C" void kernel_launch(void* const* d_in, const int* in_sizes, int n_in,
                              void* d_out, int out_size, void* d_ws, size_t ws_size,
                              hipStream_t stream) {
  (void)in_sizes; (void)n_in; (void)out_size; (void)ws_size;
  const float* local = (const float*)d_in[0];
  const float* dist  = (const float*)d_in[1];
  const float* sites = (const float*)d_in[2];
  const int*   mask  = (const int*)d_in[3];
  const float* Wq   = (const float*)d_in[4];
  const float* bq   = (const float*)d_in[5];
  const float* gq   = (const float*)d_in[6];
  const float* betq = (const float*)d_in[7];
  const float* Wk   = (const float*)d_in[8];
  const float* bk   = (const float*)d_in[9];
  const float* gk   = (const float*)d_in[10];
  const float* betk = (const float*)d_in[11];
  const float* Wv   = (const float*)d_in[12];
  const float* bv   = (const float*)d_in[13];
  const float* gv   = (const float*)d_in[14];
  const float* betv = (const float*)d_in[15];
  const float* g1   = (const float*)d_in[16];
  const float* b1   = (const float*)d_in[17];
  const float* Wo   = (const float*)d_in[18];
  const float* bo   = (const float*)d_in[19];
  const float* g2   = (const float*)d_in[20];
  const float* b2   = (const float*)d_in[21];
  const float* beta_a = (const float*)d_in[25];
  float* out = (float*)d_out;

  float* ws = (float*)d_ws;
  float* MkP   = ws;               // 4*65536
  float* MvP   = MkP + 262144;     // 4*65536
  float* Mk    = MvP + 262144;     // 65536
  float* Mv    = Mk + 65536;       // 65536
  float* kmeta = Mv + 65536;       // 1024
  float* vmeta = kmeta + 1024;     // 1024
  float* q_ln  = vmeta + 1024;     // 262144
  float* wkeff = q_ln + 262144;    // 262144
  float* cbGT  = wkeff + 262144;   // 4096
  float* mk_arr = cbGT + 4096;     // 32768
  float* sk_arr = mk_arr + 32768;  // 32768
  float* mv_arr = sk_arr + 32768;  // 32768
  float* sv_arr = mv_arr + 32768;  // 32768
  float* zbuf  = sv_arr + 32768;   // 262144
  float* bg    = zbuf + 262144;    // 2048

  k_meta<<<dim3(256, 2), dim3(256), 0, stream>>>(Wk, bk, Wv, bv, kmeta, vmeta);
  k_aat<<<dim3(8, 8, 8), dim3(256), 0, stream>>>(Wk, Wv, MkP, MvP);
  k_aat_reduce<<<dim3(256, 2), dim3(256), 0, stream>>>(MkP, MvP, Mk, Mv);
  k_qln<<<dim3(128), dim3(256), 0, stream>>>(local, Wq, bq, gq, betq, q_ln);
  k_wkeff<<<dim3(8, 128), dim3(256), 0, stream>>>(q_ln, Wk, bk, gk, betk, wkeff, cbGT);
  k_moments<<<dim3(1024, 2), dim3(256), 0, stream>>>(dist, sites, Mk, Mv, kmeta, vmeta,
                                                     mk_arr, sk_arr, mv_arr, sv_arr);
  k_attn<<<dim3(128), dim3(256), 0, stream>>>(dist, sites, mask, wkeff, cbGT,
                                              mk_arr, sk_arr, mv_arr, sv_arr, zbuf, bg);
  k_out<<<dim3(128), dim3(256), 0, stream>>>(zbuf, bg, q_ln, Wv, bv, gv, betv,
                                             g1, b1, Wo, bo, g2, b2, beta_a, out);
}

// Round 2
// 341.059 us; speedup vs baseline: 1.1496x; 1.1496x over previous
//
#include <hip/hip_runtime.h>

#define NB 128
#define NS 256
#define ND 256
#define NH 8
#define NHD 2048
static constexpr float EPS = 1e-5f;

typedef __attribute__((ext_vector_type(8))) short bf8v;
typedef __attribute__((ext_vector_type(4))) float f32x4;

__device__ __forceinline__ short f2bf(float f) {
  unsigned u = __float_as_uint(f);
  unsigned r = (u + 0x7fffu + ((u >> 16) & 1u)) >> 16;
  return (short)r;
}

// ---------- helpers ----------
__device__ __forceinline__ float block_reduce_sum(float v, float* red, int t) {
  __syncthreads();
  red[t] = v;
  __syncthreads();
  for (int off = 128; off > 0; off >>= 1) {
    if (t < off) red[t] += red[t + off];
    __syncthreads();
  }
  return red[0];
}

// ---------- K0: per-matrix meta ----------
__global__ __launch_bounds__(256) void k_meta(const float* __restrict__ Wk,
                                              const float* __restrict__ bk,
                                              const float* __restrict__ Wv,
                                              const float* __restrict__ bv,
                                              float* __restrict__ kmeta,
                                              float* __restrict__ vmeta) {
  int sel = blockIdx.y, c = blockIdx.x, t = threadIdx.x;
  const float* W = sel ? Wv : Wk;
  const float* bvec = sel ? bv : bk;
  float* meta = sel ? vmeta : kmeta;
  __shared__ float red[256];
  float s_w = 0.f, s_l = 0.f;
  const float* row = W + (size_t)c * NHD;
  for (int j = t; j < NHD; j += 256) { float w = row[j]; s_w += w; s_l += w * bvec[j]; }
  s_w = block_reduce_sum(s_w, red, t);
  s_l = block_reduce_sum(s_l, red, t);
  if (t == 0) { meta[c] = s_w * (1.0f / NHD); meta[256 + c] = s_l * (2.0f / NHD); }
  if (c == 0) {
    float s_b = 0.f, s_b2 = 0.f;
    for (int j = t; j < NHD; j += 256) { float bb = bvec[j]; s_b += bb; s_b2 += bb * bb; }
    s_b = block_reduce_sum(s_b, red, t);
    s_b2 = block_reduce_sum(s_b2, red, t);
    if (t == 0) { meta[512] = s_b * (1.0f / NHD); meta[513] = s_b2 * (1.0f / NHD); }
  }
}

// ---------- K2a: partial A*A^T over K-slices ----------
__global__ __launch_bounds__(256) void k_aat(const float* __restrict__ Wk,
                                             const float* __restrict__ Wv,
                                             float* __restrict__ MkP,
                                             float* __restrict__ MvP) {
  int bi = blockIdx.x, bj = blockIdx.y;
  int sel = blockIdx.z & 1, ks = blockIdx.z >> 1;
  const float* A = sel ? Wv : Wk;
  float* outP = (sel ? MvP : MkP) + ks * (256 * 256);
  int t = threadIdx.x;
  __shared__ float As[32][129];
  __shared__ float Bs[32][129];
  int ty = t >> 4, tx = t & 15;
  float a00 = 0.f, a01 = 0.f, a10 = 0.f, a11 = 0.f;
  for (int kc = 0; kc < 4; ++kc) {
    int k0 = ks * 512 + kc * 128;
    __syncthreads();
    for (int i = 0; i < 16; ++i) {
      int li = t + 256 * i;
      int r = li >> 7, cc = li & 127;
      As[r][cc] = A[(size_t)(bi * 32 + r) * NHD + k0 + cc];
      Bs[r][cc] = A[(size_t)(bj * 32 + r) * NHD + k0 + cc];
    }
    __syncthreads();
    for (int k = 0; k < 128; ++k) {
      float x0 = As[ty][k], x1 = As[ty + 16][k];
      float y0 = Bs[tx][k], y1 = Bs[tx + 16][k];
      a00 = fmaf(x0, y0, a00); a01 = fmaf(x0, y1, a01);
      a10 = fmaf(x1, y0, a10); a11 = fmaf(x1, y1, a11);
    }
  }
  int r0 = bi * 32 + ty, c0 = bj * 32 + tx;
  outP[r0 * 256 + c0] = a00;
  outP[r0 * 256 + c0 + 16] = a01;
  outP[(r0 + 16) * 256 + c0] = a10;
  outP[(r0 + 16) * 256 + c0 + 16] = a11;
}

// reduce partials -> bf16 M (row-major; M symmetric)
__global__ __launch_bounds__(256) void k_aat_reduce(const float* __restrict__ MkP,
                                                    const float* __restrict__ MvP,
                                                    short* __restrict__ Mkb,
                                                    short* __restrict__ Mvb) {
  int sel = blockIdx.y;
  const float* P = sel ? MvP : MkP;
  short* O = sel ? Mvb : Mkb;
  int idx = blockIdx.x * 256 + threadIdx.x;
  float s = (P[idx] + P[65536 + idx] + P[131072 + idx] + P[196608 + idx]) * (1.0f / NHD);
  O[idx] = f2bf(s);
}

// ---------- K3: q = LN(local @ Wq + bq) ----------
__global__ __launch_bounds__(256) void k_qln(const float* __restrict__ local,
                                             const float* __restrict__ Wq,
                                             const float* __restrict__ bq,
                                             const float* __restrict__ gq,
                                             const float* __restrict__ betq,
                                             float* __restrict__ q_ln) {
  int b = blockIdx.x, t = threadIdx.x;
  __shared__ float ls[256];
  __shared__ float red[256];
  ls[t] = local[b * ND + t];
  __syncthreads();
  float acc[8];
#pragma unroll
  for (int r = 0; r < 8; ++r) acc[r] = bq[r * 256 + t];
  for (int c = 0; c < ND; ++c) {
    float lv = ls[c];
    const float* wrow = Wq + (size_t)c * NHD + t;
#pragma unroll
    for (int r = 0; r < 8; ++r) acc[r] = fmaf(lv, wrow[r * 256], acc[r]);
  }
  float s1 = 0.f, s2 = 0.f;
#pragma unroll
  for (int r = 0; r < 8; ++r) { s1 += acc[r]; s2 += acc[r] * acc[r]; }
  s1 = block_reduce_sum(s1, red, t);
  s2 = block_reduce_sum(s2, red, t);
  float m = s1 * (1.0f / NHD);
  float var = s2 * (1.0f / NHD) - m * m;
  float is = 1.0f / sqrtf(var + EPS);
#pragma unroll
  for (int r = 0; r < 8; ++r) {
    int j = r * 256 + t;
    q_ln[(size_t)b * NHD + j] = (acc[r] - m) * is * gq[j] + betq[j];
  }
}

// ---------- K4: wkeff ----------
__global__ __launch_bounds__(256) void k_wkeff(const float* __restrict__ q_ln,
                                               const float* __restrict__ Wk,
                                               const float* __restrict__ bk,
                                               const float* __restrict__ gk,
                                               const float* __restrict__ betk,
                                               float* __restrict__ wkeff,
                                               float* __restrict__ cbGT) {
  int h = blockIdx.x, b = blockIdx.y, t = threadIdx.x;
  __shared__ float qg[256];
  __shared__ float red[256];
  int j = h * 256 + t;
  float q = q_ln[(size_t)b * NHD + j];
  float qgv = q * gk[j];
  qg[t] = qgv;
  float cb = block_reduce_sum(bk[j] * qgv, red, t);
  float G = block_reduce_sum(qgv, red, t);
  float T = block_reduce_sum(q * betk[j], red, t);
  float acc = 0.f;
  const float4* wr = (const float4*)(Wk + (size_t)t * NHD + h * 256);
#pragma unroll 4
  for (int d4 = 0; d4 < 64; ++d4) {
    float4 w = wr[d4];
    acc += w.x * qg[d4 * 4] + w.y * qg[d4 * 4 + 1] + w.z * qg[d4 * 4 + 2] + w.w * qg[d4 * 4 + 3];
  }
  wkeff[(size_t)(b * NH + h) * ND + t] = acc;
  if (t == 0) { float* p = cbGT + (b * NH + h) * 4; p[0] = cb; p[1] = G; p[2] = T; }
}

// ---------- mask-format detect (once) ----------
__global__ __launch_bounds__(256) void k_maskflag(const int* __restrict__ mask_i,
                                                  int* __restrict__ flag) {
  __shared__ int s;
  int t = threadIdx.x;
  if (t == 0) s = 0;
  __syncthreads();
  int any = 0;
  for (int i = t; i < 8192; i += 256) {
    unsigned v = (unsigned)mask_i[i];
    if (v > 1u) any = 1;
  }
  if (any) atomicOr(&s, 1);
  __syncthreads();
  if (t == 0) flag[0] = s;
}

// ---------- K5a (MFMA): LN moments via y = x^T M x, M bf16, step2 via MFMA ----------
// Per wave: 32 rows (2 groups of 16). A-frags from global fp32 X (converted),
// B-frags from L2-resident bf16 M (symmetric). Step2: Y = T * X16^T with
// B-operand = the X A-frags (A-layout == B-layout content-wise), A-operand = T
// round-tripped bf16 through wave-private LDS. diag(Y) = rowsum(T .* X).
__global__ __launch_bounds__(256) void k_moments(const float* __restrict__ dist,
                                                 const float* __restrict__ sites,
                                                 const short* __restrict__ Mkb,
                                                 const short* __restrict__ Mvb,
                                                 const float* __restrict__ kmeta,
                                                 const float* __restrict__ vmeta,
                                                 float* __restrict__ mk_arr,
                                                 float* __restrict__ sk_arr,
                                                 float* __restrict__ mv_arr,
                                                 float* __restrict__ sv_arr) {
  int sel = blockIdx.y;
  const float* X = sel ? sites : dist;
  const short* Mb = sel ? Mvb : Mkb;
  const float* meta = sel ? vmeta : kmeta;
  float* m_out = sel ? mv_arr : mk_arr;
  float* s_out = sel ? sv_arr : sk_arr;

  int t = threadIdx.x;
  int w = t >> 6;            // wave id 0..3
  int l = t & 63;            // lane
  int r16 = l & 15;          // A-row within 16-group / B-col
  int ksub = l >> 4;         // k sub-block 0..3

  __shared__ __align__(16) short Tb[4][2][16][40];

  size_t rowA = (size_t)blockIdx.x * 128 + w * 32;
  const float* xr0 = X + (rowA + r16) * 256;
  const float* xr1 = xr0 + 16 * 256;

  bf8v af0[8], af1[8];
  float pm0 = 0.f, pl0 = 0.f, pm1 = 0.f, pl1 = 0.f;
#pragma unroll
  for (int kc = 0; kc < 8; ++kc) {
    int c0 = kc * 32 + ksub * 8;
    float4 wa = *(const float4*)(meta + c0);
    float4 wb = *(const float4*)(meta + c0 + 4);
    float4 la = *(const float4*)(meta + 256 + c0);
    float4 lb = *(const float4*)(meta + 256 + c0 + 4);
    float4 x0a = *(const float4*)(xr0 + c0);
    float4 x0b = *(const float4*)(xr0 + c0 + 4);
    float4 x1a = *(const float4*)(xr1 + c0);
    float4 x1b = *(const float4*)(xr1 + c0 + 4);
    pm0 += x0a.x * wa.x + x0a.y * wa.y + x0a.z * wa.z + x0a.w * wa.w
         + x0b.x * wb.x + x0b.y * wb.y + x0b.z * wb.z + x0b.w * wb.w;
    pl0 += x0a.x * la.x + x0a.y * la.y + x0a.z * la.z + x0a.w * la.w
         + x0b.x * lb.x + x0b.y * lb.y + x0b.z * lb.z + x0b.w * lb.w;
    pm1 += x1a.x * wa.x + x1a.y * wa.y + x1a.z * wa.z + x1a.w * wa.w
         + x1b.x * wb.x + x1b.y * wb.y + x1b.z * wb.z + x1b.w * wb.w;
    pl1 += x1a.x * la.x + x1a.y * la.y + x1a.z * la.z + x1a.w * la.w
         + x1b.x * lb.x + x1b.y * lb.y + x1b.z * lb.z + x1b.w * lb.w;
    bf8v a0, a1;
    a0[0] = f2bf(x0a.x); a0[1] = f2bf(x0a.y); a0[2] = f2bf(x0a.z); a0[3] = f2bf(x0a.w);
    a0[4] = f2bf(x0b.x); a0[5] = f2bf(x0b.y); a0[6] = f2bf(x0b.z); a0[7] = f2bf(x0b.w);
    a1[0] = f2bf(x1a.x); a1[1] = f2bf(x1a.y); a1[2] = f2bf(x1a.z); a1[3] = f2bf(x1a.w);
    a1[4] = f2bf(x1b.x); a1[5] = f2bf(x1b.y); a1[6] = f2bf(x1b.z); a1[7] = f2bf(x1b.w);
    af0[kc] = a0;
    af1[kc] = a1;
  }
  // reduce mean/lin partials across the 4 ksub lanes sharing r16
  pm0 += __shfl_xor(pm0, 16); pm0 += __shfl_xor(pm0, 32);
  pl0 += __shfl_xor(pl0, 16); pl0 += __shfl_xor(pl0, 32);
  pm1 += __shfl_xor(pm1, 16); pm1 += __shfl_xor(pm1, 32);
  pl1 += __shfl_xor(pl1, 16); pl1 += __shfl_xor(pl1, 32);

  f32x4 y0 = {0.f, 0.f, 0.f, 0.f}, y1 = {0.f, 0.f, 0.f, 0.f};

#pragma unroll
  for (int n = 0; n < 16; ++n) {
    bf8v bf[8];
#pragma unroll
    for (int kc = 0; kc < 8; ++kc)
      bf[kc] = *(const bf8v*)(Mb + ((size_t)(n * 16 + r16) << 8) + kc * 32 + ksub * 8);
    f32x4 ta = {0.f, 0.f, 0.f, 0.f}, tb = {0.f, 0.f, 0.f, 0.f};
#pragma unroll
    for (int kc = 0; kc < 8; ++kc) {
      ta = __builtin_amdgcn_mfma_f32_16x16x32_bf16(af0[kc], bf[kc], ta, 0, 0, 0);
      tb = __builtin_amdgcn_mfma_f32_16x16x32_bf16(af1[kc], bf[kc], tb, 0, 0, 0);
    }
    // T tile (D-layout: row=ksub*4+q, col=r16) -> bf16 into wave-private LDS
#pragma unroll
    for (int q = 0; q < 4; ++q) {
      Tb[w][0][ksub * 4 + q][(n & 1) * 16 + r16] = f2bf(ta[q]);
      Tb[w][1][ksub * 4 + q][(n & 1) * 16 + r16] = f2bf(tb[q]);
    }
    if (n & 1) {
      bf8v a20 = *(const bf8v*)&Tb[w][0][r16][ksub * 8];
      bf8v a21 = *(const bf8v*)&Tb[w][1][r16][ksub * 8];
      y0 = __builtin_amdgcn_mfma_f32_16x16x32_bf16(a20, af0[n >> 1], y0, 0, 0, 0);
      y1 = __builtin_amdgcn_mfma_f32_16x16x32_bf16(a21, af1[n >> 1], y1, 0, 0, 0);
    }
  }

  // diag extraction: lane holds Y[ksub*4+q][r16]; diag lane: ksub == r16>>2, q = r16&3
  int qs = r16 & 3;
  float yd0 = (qs == 0) ? y0[0] : (qs == 1) ? y0[1] : (qs == 2) ? y0[2] : y0[3];
  float yd1 = (qs == 0) ? y1[0] : (qs == 1) ? y1[1] : (qs == 2) ? y1[2] : y1[3];
  float bbar = meta[512], cc = meta[513];
  if (ksub == (r16 >> 2)) {
    float m0 = pm0 + bbar;
    float var0 = fmaxf(yd0 + (pl0 + cc) - m0 * m0, 0.0f) + EPS;
    m_out[rowA + r16] = m0;
    s_out[rowA + r16] = 1.0f / sqrtf(var0);
    float m1 = pm1 + bbar;
    float var1 = fmaxf(yd1 + (pl1 + cc) - m1 * m1, 0.0f) + EPS;
    m_out[rowA + 16 + r16] = m1;
    s_out[rowA + 16 + r16] = 1.0f / sqrtf(var1);
  }
}

// ---------- K5: attention scores + softmax + weighted site accumulation (head-split) ----------
__global__ __launch_bounds__(256) void k_attn(const float* __restrict__ dist,
                                              const float* __restrict__ sites,
                                              const int* __restrict__ mask_i,
                                              const int* __restrict__ mflag,
                                              const float* __restrict__ wkeff,
                                              const float* __restrict__ cbGT,
                                              const float* __restrict__ mk_arr,
                                              const float* __restrict__ sk_arr,
                                              const float* __restrict__ mv_arr,
                                              const float* __restrict__ sv_arr,
                                              float* __restrict__ zbuf,
                                              float* __restrict__ bg) {
  int b = blockIdx.x, hb = blockIdx.y, t = threadIdx.x;
  int h0 = hb * 4;
  __shared__ float Xs[64][257];
  __shared__ float wks[4][256];
  __shared__ float us[4][260];
  __shared__ float cbs[4], Gs[4], Ts4[4];

  for (int i = 0; i < 4; ++i) wks[i][t] = wkeff[(size_t)(b * NH + h0 + i) * ND + t];
  if (t < 4) {
    const float* p = cbGT + (b * NH + h0 + t) * 4;
    cbs[t] = p[0]; Gs[t] = p[1]; Ts4[t] = p[2];
  }
  __syncthreads();
  const int mbytes = mflag[0];
  const unsigned char* mask_b = (const unsigned char*)mask_i;
  int hg = t >> 6, sl = t & 63;

  for (int chunk = 0; chunk < 4; ++chunk) {
    const float* Xb = dist + ((size_t)b * NS + chunk * 64) * ND;
    for (int i = 0; i < 64; ++i) {
      int li = t + 256 * i;
      Xs[li >> 8][li & 255] = Xb[li];
    }
    __syncthreads();
    int s = chunk * 64 + sl;
    float mks = mk_arr[b * NS + s], sks = sk_arr[b * NS + s];
    int mbit = mbytes ? (int)mask_b[b * NS + s] : mask_i[b * NS + s];
    float d0 = 0.f;
#pragma unroll 4
    for (int c = 0; c < 256; ++c) d0 = fmaf(Xs[sl][c], wks[hg][c], d0);
    float u0 = ((d0 + cbs[hg] - mks * Gs[hg]) * sks + Ts4[hg]) * 0.0625f;
    if (mbit) u0 = -1e30f;
    us[hg][s] = u0;
    __syncthreads();
  }

  // per-head softmax across 256 sites (one wave per head)
  float vals[4];
  float mx = -3.0e38f;
#pragma unroll
  for (int i = 0; i < 4; ++i) { vals[i] = us[hg][sl + 64 * i]; mx = fmaxf(mx, vals[i]); }
  for (int off = 32; off > 0; off >>= 1) mx = fmaxf(mx, __shfl_xor(mx, off));
  float sum = 0.f;
#pragma unroll
  for (int i = 0; i < 4; ++i) { vals[i] = expf(vals[i] - mx); sum += vals[i]; }
  for (int off = 32; off > 0; off >>= 1) sum += __shfl_xor(sum, off);
  float inv = 1.0f / sum;
  float bpart = 0.f, gpart = 0.f;
#pragma unroll
  for (int i = 0; i < 4; ++i) {
    int s = sl + 64 * i;
    float a = vals[i] * inv;
    float sv = sv_arr[b * NS + s];
    float mv = mv_arr[b * NS + s];
    float wv = a * sv;
    us[hg][s] = wv;  // attn / sigma_v
    bpart += wv;
    gpart += wv * mv;
  }
  for (int off = 32; off > 0; off >>= 1) {
    bpart += __shfl_xor(bpart, off);
    gpart += __shfl_xor(gpart, off);
  }
  if (sl == 0) { float* p = bg + (b * NH + h0 + hg) * 2; p[0] = bpart; p[1] = gpart; }

  // z[h,c] = sum_s w[h,s] * sites[b,s,c]
  float accz[4];
#pragma unroll
  for (int i = 0; i < 4; ++i) accz[i] = 0.f;
  for (int chunk = 0; chunk < 4; ++chunk) {
    __syncthreads();
    const float* Xb = sites + ((size_t)b * NS + chunk * 64) * ND;
    for (int i = 0; i < 64; ++i) {
      int li = t + 256 * i;
      Xs[li >> 8][li & 255] = Xb[li];
    }
    __syncthreads();
    for (int s0 = 0; s0 < 64; ++s0) {
      float x = Xs[s0][t];
      int s = chunk * 64 + s0;
#pragma unroll
      for (int hh = 0; hh < 4; ++hh) accz[hh] = fmaf(us[hh][s], x, accz[hh]);
    }
  }
#pragma unroll
  for (int hh = 0; hh < 4; ++hh) zbuf[(size_t)(b * NH + h0 + hh) * ND + t] = accz[hh];
}

// ---------- K6: z@Wv, residual, LN1, @Wo, LN2 ; constant 'a' output ----------
__global__ __launch_bounds__(256) void k_out(const float* __restrict__ zbuf,
                                             const float* __restrict__ bg,
                                             const float* __restrict__ q_ln,
                                             const float* __restrict__ Wv,
                                             const float* __restrict__ bv,
                                             const float* __restrict__ gv,
                                             const float* __restrict__ betv,
                                             const float* __restrict__ g1,
                                             const float* __restrict__ b1,
                                             const float* __restrict__ Wo,
                                             const float* __restrict__ bo,
                                             const float* __restrict__ g2,
                                             const float* __restrict__ b2,
                                             const float* __restrict__ beta_a,
                                             float* __restrict__ out) {
  int b = blockIdx.x, t = threadIdx.x;
  __shared__ float zs[8][257];
  __shared__ float y1s[2048];
  __shared__ float red[256];
  __shared__ float bets[8], gams[8];
  for (int i = 0; i < 8; ++i) zs[i][t] = zbuf[(size_t)(b * NH + i) * ND + t];
  if (t < 8) { const float* p = bg + (b * NH + t) * 2; bets[t] = p[0]; gams[t] = p[1]; }
  __syncthreads();
  float acc[8];
#pragma unroll
  for (int r = 0; r < 8; ++r) acc[r] = 0.f;
  for (int c = 0; c < 256; ++c) {
    const float* wrow = Wv + (size_t)c * NHD + t;
#pragma unroll
    for (int r = 0; r < 8; ++r) acc[r] = fmaf(zs[r][c], wrow[r * 256], acc[r]);
  }
  float s1 = 0.f, s2 = 0.f;
  float vv[8];
#pragma unroll
  for (int r = 0; r < 8; ++r) {
    int j = r * 256 + t;
    float av = gv[j] * (acc[r] + bv[j] * bets[r] - gams[r]) + betv[j];
    float o = av + q_ln[(size_t)b * NHD + j];
    vv[r] = o;
    s1 += o;
    s2 += o * o;
  }
  s1 = block_reduce_sum(s1, red, t);
  s2 = block_reduce_sum(s2, red, t);
  float m = s1 * (1.0f / NHD);
  float var = s2 * (1.0f / NHD) - m * m;
  float is = 1.0f / sqrtf(var + EPS);
#pragma unroll
  for (int r = 0; r < 8; ++r) {
    int j = r * 256 + t;
    y1s[j] = (vv[r] - m) * is * g1[j] + b1[j];
  }
  __syncthreads();
  float acc2 = bo[t];
  for (int jj = 0; jj < 2048; ++jj) acc2 = fmaf(y1s[jj], Wo[(size_t)jj * 256 + t], acc2);
  float q1 = block_reduce_sum(acc2, red, t);
  float q2 = block_reduce_sum(acc2 * acc2, red, t);
  float m2 = q1 * (1.0f / 256.0f);
  float v2 = q2 * (1.0f / 256.0f) - m2 * m2;
  float is2 = 1.0f / sqrtf(v2 + EPS);
  out[NB * NS + b * 256 + t] = (acc2 - m2) * is2 * g2[t] + b2[t];
  out[b * 256 + t] = beta_a[0];
}

extern "C" void kernel_launch(void* const* d_in, const int* in_sizes, int n_in,
                              void* d_out, int out_size, void* d_ws, size_t ws_size,
                              hipStream_t stream) {
  (void)in_sizes; (void)n_in; (void)out_size; (void)ws_size;
  const float* local = (const float*)d_in[0];
  const float* dist  = (const float*)d_in[1];
  const float* sites = (const float*)d_in[2];
  const int*   mask  = (const int*)d_in[3];
  const float* Wq   = (const float*)d_in[4];
  const float* bq   = (const float*)d_in[5];
  const float* gq   = (const float*)d_in[6];
  const float* betq = (const float*)d_in[7];
  const float* Wk   = (const float*)d_in[8];
  const float* bk   = (const float*)d_in[9];
  const float* gk   = (const float*)d_in[10];
  const float* betk = (const float*)d_in[11];
  const float* Wv   = (const float*)d_in[12];
  const float* bv   = (const float*)d_in[13];
  const float* gv   = (const float*)d_in[14];
  const float* betv = (const float*)d_in[15];
  const float* g1   = (const float*)d_in[16];
  const float* b1   = (const float*)d_in[17];
  const float* Wo   = (const float*)d_in[18];
  const float* bo   = (const float*)d_in[19];
  const float* g2   = (const float*)d_in[20];
  const float* b2   = (const float*)d_in[21];
  const float* beta_a = (const float*)d_in[25];
  float* out = (float*)d_out;

  float* ws = (float*)d_ws;
  float* MkP   = ws;                // 262144
  float* MvP   = MkP + 262144;      // 262144
  short* Mkb   = (short*)(MvP + 262144);   // 65536 shorts = 32768 float-slots
  short* Mvb   = Mkb + 65536;              // 65536 shorts
  float* kmeta = (float*)(Mvb + 65536);    // 1024
  float* vmeta = kmeta + 1024;      // 1024
  float* q_ln  = vmeta + 1024;      // 262144
  float* wkeff = q_ln + 262144;     // 262144
  float* cbGT  = wkeff + 262144;    // 4096
  float* mk_arr = cbGT + 4096;      // 32768
  float* sk_arr = mk_arr + 32768;   // 32768
  float* mv_arr = sk_arr + 32768;   // 32768
  float* sv_arr = mv_arr + 32768;   // 32768
  float* zbuf  = sv_arr + 32768;    // 262144
  float* bg    = zbuf + 262144;     // 2048
  int*   mflag = (int*)(bg + 2048); // 16

  k_meta<<<dim3(256, 2), dim3(256), 0, stream>>>(Wk, bk, Wv, bv, kmeta, vmeta);
  k_aat<<<dim3(8, 8, 8), dim3(256), 0, stream>>>(Wk, Wv, MkP, MvP);
  k_aat_reduce<<<dim3(256, 2), dim3(256), 0, stream>>>(MkP, MvP, Mkb, Mvb);
  k_qln<<<dim3(128), dim3(256), 0, stream>>>(local, Wq, bq, gq, betq, q_ln);
  k_wkeff<<<dim3(8, 128), dim3(256), 0, stream>>>(q_ln, Wk, bk, gk, betk, wkeff, cbGT);
  k_maskflag<<<dim3(1), dim3(256), 0, stream>>>(mask, mflag);
  k_moments<<<dim3(256, 2), dim3(256), 0, stream>>>(dist, sites, Mkb, Mvb, kmeta, vmeta,
                                                    mk_arr, sk_arr, mv_arr, sv_arr);
  k_attn<<<dim3(128, 2), dim3(256), 0, stream>>>(dist, sites, mask, mflag, wkeff, cbGT,
                                                 mk_arr, sk_arr, mv_arr, sv_arr, zbuf, bg);
  k_out<<<dim3(128), dim3(256), 0, stream>>>(zbuf, bg, q_ln, Wv, bv, gv, betv,
                                             g1, b1, Wo, bo, g2, b2, beta_a, out);
}

// Round 3
// 271.578 us; speedup vs baseline: 1.4437x; 1.2558x over previous
//
#include <hip/hip_runtime.h>

#define NB 128
#define NS 256
#define ND 256
#define NH 8
#define NHD 2048
static constexpr float EPS = 1e-5f;

typedef __attribute__((ext_vector_type(8))) short bf8v;
typedef __attribute__((ext_vector_type(4))) float f32x4;

__device__ __forceinline__ short f2bf(float f) {
  unsigned u = __float_as_uint(f);
  unsigned r = (u + 0x7fffu + ((u >> 16) & 1u)) >> 16;
  return (short)r;
}

__device__ __forceinline__ void split8(float4 a, float4 b, bf8v& hi, bf8v& lo) {
  float x[8] = {a.x, a.y, a.z, a.w, b.x, b.y, b.z, b.w};
  bf8v h, l;
#pragma unroll
  for (int i = 0; i < 8; ++i) {
    unsigned u = __float_as_uint(x[i]);
    unsigned hb = (u + 0x7fffu + ((u >> 16) & 1u)) >> 16;
    h[i] = (short)hb;
    float hf = __uint_as_float(hb << 16);
    l[i] = f2bf(x[i] - hf);
  }
  hi = h;
  lo = l;
}

// ---------- helpers ----------
__device__ __forceinline__ float block_reduce_sum(float v, float* red, int t) {
  __syncthreads();
  red[t] = v;
  __syncthreads();
  for (int off = 128; off > 0; off >>= 1) {
    if (t < off) red[t] += red[t + off];
    __syncthreads();
  }
  return red[0];
}

// ---------- K0: per-matrix meta ----------
__global__ __launch_bounds__(256) void k_meta(const float* __restrict__ Wk,
                                              const float* __restrict__ bk,
                                              const float* __restrict__ Wv,
                                              const float* __restrict__ bv,
                                              float* __restrict__ kmeta,
                                              float* __restrict__ vmeta) {
  int sel = blockIdx.y, c = blockIdx.x, t = threadIdx.x;
  const float* W = sel ? Wv : Wk;
  const float* bvec = sel ? bv : bk;
  float* meta = sel ? vmeta : kmeta;
  __shared__ float red[256];
  float s_w = 0.f, s_l = 0.f;
  const float* row = W + (size_t)c * NHD;
  for (int j = t; j < NHD; j += 256) { float w = row[j]; s_w += w; s_l += w * bvec[j]; }
  s_w = block_reduce_sum(s_w, red, t);
  s_l = block_reduce_sum(s_l, red, t);
  if (t == 0) { meta[c] = s_w * (1.0f / NHD); meta[256 + c] = s_l * (2.0f / NHD); }
  if (c == 0) {
    float s_b = 0.f, s_b2 = 0.f;
    for (int j = t; j < NHD; j += 256) { float bb = bvec[j]; s_b += bb; s_b2 += bb * bb; }
    s_b = block_reduce_sum(s_b, red, t);
    s_b2 = block_reduce_sum(s_b2, red, t);
    if (t == 0) { meta[512] = s_b * (1.0f / NHD); meta[513] = s_b2 * (1.0f / NHD); }
  }
}

// ---------- K2a: partial A*A^T over K-slices ----------
__global__ __launch_bounds__(256) void k_aat(const float* __restrict__ Wk,
                                             const float* __restrict__ Wv,
                                             float* __restrict__ MkP,
                                             float* __restrict__ MvP) {
  int bi = blockIdx.x, bj = blockIdx.y;
  int sel = blockIdx.z & 1, ks = blockIdx.z >> 1;
  const float* A = sel ? Wv : Wk;
  float* outP = (sel ? MvP : MkP) + ks * (256 * 256);
  int t = threadIdx.x;
  __shared__ float As[32][129];
  __shared__ float Bs[32][129];
  int ty = t >> 4, tx = t & 15;
  float a00 = 0.f, a01 = 0.f, a10 = 0.f, a11 = 0.f;
  for (int kc = 0; kc < 4; ++kc) {
    int k0 = ks * 512 + kc * 128;
    __syncthreads();
    for (int i = 0; i < 16; ++i) {
      int li = t + 256 * i;
      int r = li >> 7, cc = li & 127;
      As[r][cc] = A[(size_t)(bi * 32 + r) * NHD + k0 + cc];
      Bs[r][cc] = A[(size_t)(bj * 32 + r) * NHD + k0 + cc];
    }
    __syncthreads();
    for (int k = 0; k < 128; ++k) {
      float x0 = As[ty][k], x1 = As[ty + 16][k];
      float y0 = Bs[tx][k], y1 = Bs[tx + 16][k];
      a00 = fmaf(x0, y0, a00); a01 = fmaf(x0, y1, a01);
      a10 = fmaf(x1, y0, a10); a11 = fmaf(x1, y1, a11);
    }
  }
  int r0 = bi * 32 + ty, c0 = bj * 32 + tx;
  outP[r0 * 256 + c0] = a00;
  outP[r0 * 256 + c0 + 16] = a01;
  outP[(r0 + 16) * 256 + c0] = a10;
  outP[(r0 + 16) * 256 + c0 + 16] = a11;
}

// reduce partials -> bf16 M (row-major; M symmetric)
__global__ __launch_bounds__(256) void k_aat_reduce(const float* __restrict__ MkP,
                                                    const float* __restrict__ MvP,
                                                    short* __restrict__ Mkb,
                                                    short* __restrict__ Mvb) {
  int sel = blockIdx.y;
  const float* P = sel ? MvP : MkP;
  short* O = sel ? Mvb : Mkb;
  int idx = blockIdx.x * 256 + threadIdx.x;
  float s = (P[idx] + P[65536 + idx] + P[131072 + idx] + P[196608 + idx]) * (1.0f / NHD);
  O[idx] = f2bf(s);
}

// ---------- K3: q = LN(local @ Wq + bq) ----------
__global__ __launch_bounds__(256) void k_qln(const float* __restrict__ local,
                                             const float* __restrict__ Wq,
                                             const float* __restrict__ bq,
                                             const float* __restrict__ gq,
                                             const float* __restrict__ betq,
                                             float* __restrict__ q_ln) {
  int b = blockIdx.x, t = threadIdx.x;
  __shared__ float ls[256];
  __shared__ float red[256];
  ls[t] = local[b * ND + t];
  __syncthreads();
  float acc[8];
#pragma unroll
  for (int r = 0; r < 8; ++r) acc[r] = bq[r * 256 + t];
  for (int c = 0; c < ND; ++c) {
    float lv = ls[c];
    const float* wrow = Wq + (size_t)c * NHD + t;
#pragma unroll
    for (int r = 0; r < 8; ++r) acc[r] = fmaf(lv, wrow[r * 256], acc[r]);
  }
  float s1 = 0.f, s2 = 0.f;
#pragma unroll
  for (int r = 0; r < 8; ++r) { s1 += acc[r]; s2 += acc[r] * acc[r]; }
  s1 = block_reduce_sum(s1, red, t);
  s2 = block_reduce_sum(s2, red, t);
  float m = s1 * (1.0f / NHD);
  float var = s2 * (1.0f / NHD) - m * m;
  float is = 1.0f / sqrtf(var + EPS);
#pragma unroll
  for (int r = 0; r < 8; ++r) {
    int j = r * 256 + t;
    q_ln[(size_t)b * NHD + j] = (acc[r] - m) * is * gq[j] + betq[j];
  }
}

// ---------- K4: wkeff ----------
__global__ __launch_bounds__(256) void k_wkeff(const float* __restrict__ q_ln,
                                               const float* __restrict__ Wk,
                                               const float* __restrict__ bk,
                                               const float* __restrict__ gk,
                                               const float* __restrict__ betk,
                                               float* __restrict__ wkeff,
                                               float* __restrict__ cbGT) {
  int h = blockIdx.x, b = blockIdx.y, t = threadIdx.x;
  __shared__ float qg[256];
  __shared__ float red[256];
  int j = h * 256 + t;
  float q = q_ln[(size_t)b * NHD + j];
  float qgv = q * gk[j];
  qg[t] = qgv;
  float cb = block_reduce_sum(bk[j] * qgv, red, t);
  float G = block_reduce_sum(qgv, red, t);
  float T = block_reduce_sum(q * betk[j], red, t);
  float acc = 0.f;
  const float4* wr = (const float4*)(Wk + (size_t)t * NHD + h * 256);
#pragma unroll 4
  for (int d4 = 0; d4 < 64; ++d4) {
    float4 w = wr[d4];
    acc += w.x * qg[d4 * 4] + w.y * qg[d4 * 4 + 1] + w.z * qg[d4 * 4 + 2] + w.w * qg[d4 * 4 + 3];
  }
  wkeff[(size_t)(b * NH + h) * ND + t] = acc;
  if (t == 0) { float* p = cbGT + (b * NH + h) * 4; p[0] = cb; p[1] = G; p[2] = T; }
}

// ---------- mask-format detect (once) ----------
__global__ __launch_bounds__(256) void k_maskflag(const int* __restrict__ mask_i,
                                                  int* __restrict__ flag) {
  __shared__ int s;
  int t = threadIdx.x;
  if (t == 0) s = 0;
  __syncthreads();
  int any = 0;
  for (int i = t; i < 8192; i += 256) {
    unsigned v = (unsigned)mask_i[i];
    if (v > 1u) any = 1;
  }
  if (any) atomicOr(&s, 1);
  __syncthreads();
  if (t == 0) flag[0] = s;
}

// ---------- K5a (MFMA): LN moments via y = x^T M x ----------
__global__ __launch_bounds__(256) void k_moments(const float* __restrict__ dist,
                                                 const float* __restrict__ sites,
                                                 const short* __restrict__ Mkb,
                                                 const short* __restrict__ Mvb,
                                                 const float* __restrict__ kmeta,
                                                 const float* __restrict__ vmeta,
                                                 float* __restrict__ mk_arr,
                                                 float* __restrict__ sk_arr,
                                                 float* __restrict__ mv_arr,
                                                 float* __restrict__ sv_arr) {
  int sel = blockIdx.y;
  const float* X = sel ? sites : dist;
  const short* Mb = sel ? Mvb : Mkb;
  const float* meta = sel ? vmeta : kmeta;
  float* m_out = sel ? mv_arr : mk_arr;
  float* s_out = sel ? sv_arr : sk_arr;

  int t = threadIdx.x;
  int w = t >> 6;
  int l = t & 63;
  int r16 = l & 15;
  int ksub = l >> 4;

  __shared__ __align__(16) short Tb[4][2][16][40];

  size_t rowA = (size_t)blockIdx.x * 128 + w * 32;
  const float* xr0 = X + (rowA + r16) * 256;
  const float* xr1 = xr0 + 16 * 256;

  bf8v af0[8], af1[8];
  float pm0 = 0.f, pl0 = 0.f, pm1 = 0.f, pl1 = 0.f;
#pragma unroll
  for (int kc = 0; kc < 8; ++kc) {
    int c0 = kc * 32 + ksub * 8;
    float4 wa = *(const float4*)(meta + c0);
    float4 wb = *(const float4*)(meta + c0 + 4);
    float4 la = *(const float4*)(meta + 256 + c0);
    float4 lb = *(const float4*)(meta + 256 + c0 + 4);
    float4 x0a = *(const float4*)(xr0 + c0);
    float4 x0b = *(const float4*)(xr0 + c0 + 4);
    float4 x1a = *(const float4*)(xr1 + c0);
    float4 x1b = *(const float4*)(xr1 + c0 + 4);
    pm0 += x0a.x * wa.x + x0a.y * wa.y + x0a.z * wa.z + x0a.w * wa.w
         + x0b.x * wb.x + x0b.y * wb.y + x0b.z * wb.z + x0b.w * wb.w;
    pl0 += x0a.x * la.x + x0a.y * la.y + x0a.z * la.z + x0a.w * la.w
         + x0b.x * lb.x + x0b.y * lb.y + x0b.z * lb.z + x0b.w * lb.w;
    pm1 += x1a.x * wa.x + x1a.y * wa.y + x1a.z * wa.z + x1a.w * wa.w
         + x1b.x * wb.x + x1b.y * wb.y + x1b.z * wb.z + x1b.w * wb.w;
    pl1 += x1a.x * la.x + x1a.y * la.y + x1a.z * la.z + x1a.w * la.w
         + x1b.x * lb.x + x1b.y * lb.y + x1b.z * lb.z + x1b.w * lb.w;
    bf8v a0, a1;
    a0[0] = f2bf(x0a.x); a0[1] = f2bf(x0a.y); a0[2] = f2bf(x0a.z); a0[3] = f2bf(x0a.w);
    a0[4] = f2bf(x0b.x); a0[5] = f2bf(x0b.y); a0[6] = f2bf(x0b.z); a0[7] = f2bf(x0b.w);
    a1[0] = f2bf(x1a.x); a1[1] = f2bf(x1a.y); a1[2] = f2bf(x1a.z); a1[3] = f2bf(x1a.w);
    a1[4] = f2bf(x1b.x); a1[5] = f2bf(x1b.y); a1[6] = f2bf(x1b.z); a1[7] = f2bf(x1b.w);
    af0[kc] = a0;
    af1[kc] = a1;
  }
  pm0 += __shfl_xor(pm0, 16); pm0 += __shfl_xor(pm0, 32);
  pl0 += __shfl_xor(pl0, 16); pl0 += __shfl_xor(pl0, 32);
  pm1 += __shfl_xor(pm1, 16); pm1 += __shfl_xor(pm1, 32);
  pl1 += __shfl_xor(pl1, 16); pl1 += __shfl_xor(pl1, 32);

  f32x4 y0 = {0.f, 0.f, 0.f, 0.f}, y1 = {0.f, 0.f, 0.f, 0.f};

#pragma unroll
  for (int n = 0; n < 16; ++n) {
    bf8v bf[8];
#pragma unroll
    for (int kc = 0; kc < 8; ++kc)
      bf[kc] = *(const bf8v*)(Mb + ((size_t)(n * 16 + r16) << 8) + kc * 32 + ksub * 8);
    f32x4 ta = {0.f, 0.f, 0.f, 0.f}, tb = {0.f, 0.f, 0.f, 0.f};
#pragma unroll
    for (int kc = 0; kc < 8; ++kc) {
      ta = __builtin_amdgcn_mfma_f32_16x16x32_bf16(af0[kc], bf[kc], ta, 0, 0, 0);
      tb = __builtin_amdgcn_mfma_f32_16x16x32_bf16(af1[kc], bf[kc], tb, 0, 0, 0);
    }
#pragma unroll
    for (int q = 0; q < 4; ++q) {
      Tb[w][0][ksub * 4 + q][(n & 1) * 16 + r16] = f2bf(ta[q]);
      Tb[w][1][ksub * 4 + q][(n & 1) * 16 + r16] = f2bf(tb[q]);
    }
    if (n & 1) {
      bf8v a20 = *(const bf8v*)&Tb[w][0][r16][ksub * 8];
      bf8v a21 = *(const bf8v*)&Tb[w][1][r16][ksub * 8];
      y0 = __builtin_amdgcn_mfma_f32_16x16x32_bf16(a20, af0[n >> 1], y0, 0, 0, 0);
      y1 = __builtin_amdgcn_mfma_f32_16x16x32_bf16(a21, af1[n >> 1], y1, 0, 0, 0);
    }
  }

  int qs = r16 & 3;
  float yd0 = (qs == 0) ? y0[0] : (qs == 1) ? y0[1] : (qs == 2) ? y0[2] : y0[3];
  float yd1 = (qs == 0) ? y1[0] : (qs == 1) ? y1[1] : (qs == 2) ? y1[2] : y1[3];
  float bbar = meta[512], cc = meta[513];
  if (ksub == (r16 >> 2)) {
    float m0 = pm0 + bbar;
    float var0 = fmaxf(yd0 + (pl0 + cc) - m0 * m0, 0.0f) + EPS;
    m_out[rowA + r16] = m0;
    s_out[rowA + r16] = 1.0f / sqrtf(var0);
    float m1 = pm1 + bbar;
    float var1 = fmaxf(yd1 + (pl1 + cc) - m1 * m1, 0.0f) + EPS;
    m_out[rowA + 16 + r16] = m1;
    s_out[rowA + 16 + r16] = 1.0f / sqrtf(var1);
  }
}

// ---------- K5 (MFMA): fused scores + softmax + PV, one block per b ----------
__global__ __launch_bounds__(512) void k_attn2(const float* __restrict__ dist,
                                               const float* __restrict__ sites,
                                               const int* __restrict__ mask_i,
                                               const int* __restrict__ mflag,
                                               const float* __restrict__ wkeff,
                                               const float* __restrict__ cbGT,
                                               const float* __restrict__ mk_arr,
                                               const float* __restrict__ sk_arr,
                                               const float* __restrict__ mv_arr,
                                               const float* __restrict__ sv_arr,
                                               float* __restrict__ zbuf,
                                               float* __restrict__ bg) {
  int b = blockIdx.x, t = threadIdx.x;
  int w = t >> 6, l = t & 63, r16 = l & 15, ksub = l >> 4;

  __shared__ float us[16][260];          // scores -> attn weights; rows 8..15 zero pad
  __shared__ __align__(16) short St[256][72];  // transposed bf16 sites chunk [c][s]

  // init pad rows 8..15 of us
  for (int i = t; i < 8 * 260; i += 512) (&us[8][0])[i] = 0.f;

  const int mbytes = mflag[0];

  // ---- phase 1: scores u[s,h] via split-bf16 MFMA ----
  const float* xr0 = dist + ((size_t)b * NS + w * 32 + r16) * ND;
  const float* xr1 = xr0 + 16 * ND;
  const float* wkp = wkeff + ((size_t)b * NH + (r16 & 7)) * ND;
  f32x4 u0 = {0.f, 0.f, 0.f, 0.f}, u1 = {0.f, 0.f, 0.f, 0.f};
#pragma unroll 2
  for (int kc = 0; kc < 8; ++kc) {
    int c0 = kc * 32 + ksub * 8;
    float4 xa = *(const float4*)(xr0 + c0);
    float4 xb = *(const float4*)(xr0 + c0 + 4);
    float4 ya = *(const float4*)(xr1 + c0);
    float4 yb = *(const float4*)(xr1 + c0 + 4);
    float4 wa = {0.f, 0.f, 0.f, 0.f}, wb = {0.f, 0.f, 0.f, 0.f};
    if (r16 < 8) { wa = *(const float4*)(wkp + c0); wb = *(const float4*)(wkp + c0 + 4); }
    bf8v xh, xl, yh, yl, wh, wl;
    split8(xa, xb, xh, xl);
    split8(ya, yb, yh, yl);
    split8(wa, wb, wh, wl);
    u0 = __builtin_amdgcn_mfma_f32_16x16x32_bf16(xh, wh, u0, 0, 0, 0);
    u0 = __builtin_amdgcn_mfma_f32_16x16x32_bf16(xl, wh, u0, 0, 0, 0);
    u0 = __builtin_amdgcn_mfma_f32_16x16x32_bf16(xh, wl, u0, 0, 0, 0);
    u1 = __builtin_amdgcn_mfma_f32_16x16x32_bf16(yh, wh, u1, 0, 0, 0);
    u1 = __builtin_amdgcn_mfma_f32_16x16x32_bf16(yl, wh, u1, 0, 0, 0);
    u1 = __builtin_amdgcn_mfma_f32_16x16x32_bf16(yh, wl, u1, 0, 0, 0);
  }

  // corrections + write scores to LDS
  float cb = 0.f, G = 0.f, T = 0.f;
  if (r16 < 8) { const float* p = cbGT + (b * NH + r16) * 4; cb = p[0]; G = p[1]; T = p[2]; }
  const unsigned char* mask_b = (const unsigned char*)mask_i;
#pragma unroll
  for (int g = 0; g < 2; ++g) {
    f32x4 uu = g ? u1 : u0;
    int base = w * 32 + g * 16 + ksub * 4;
    float4 mk4 = *(const float4*)(mk_arr + b * NS + base);
    float4 sk4 = *(const float4*)(sk_arr + b * NS + base);
    int mm[4];
    if (mbytes) {
      mm[0] = mask_b[b * NS + base];     mm[1] = mask_b[b * NS + base + 1];
      mm[2] = mask_b[b * NS + base + 2]; mm[3] = mask_b[b * NS + base + 3];
    } else {
      mm[0] = mask_i[b * NS + base];     mm[1] = mask_i[b * NS + base + 1];
      mm[2] = mask_i[b * NS + base + 2]; mm[3] = mask_i[b * NS + base + 3];
    }
    const float* mkp = (const float*)&mk4;
    const float* skp = (const float*)&sk4;
#pragma unroll
    for (int q = 0; q < 4; ++q) {
      float u = ((uu[q] + cb - mkp[q] * G) * skp[q] + T) * 0.0625f;
      if (mm[q]) u = -1e30f;
      if (r16 < 8) us[r16][base + q] = u;
    }
  }
  __syncthreads();

  // ---- softmax: wave w handles head h = w ----
  {
    int h = w;
    float v[4];
#pragma unroll
    for (int i = 0; i < 4; ++i) v[i] = us[h][l + 64 * i];
    float mx = fmaxf(fmaxf(v[0], v[1]), fmaxf(v[2], v[3]));
    for (int off = 32; off > 0; off >>= 1) mx = fmaxf(mx, __shfl_xor(mx, off));
    float sum = 0.f;
#pragma unroll
    for (int i = 0; i < 4; ++i) { v[i] = expf(v[i] - mx); sum += v[i]; }
    for (int off = 32; off > 0; off >>= 1) sum += __shfl_xor(sum, off);
    float inv = 1.0f / sum;
    float bp = 0.f, gp = 0.f;
#pragma unroll
    for (int i = 0; i < 4; ++i) {
      int s = l + 64 * i;
      float a = v[i] * inv;
      float sv = sv_arr[b * NS + s];
      float mv = mv_arr[b * NS + s];
      float wv = a * sv;
      us[h][s] = wv;
      bp += wv;
      gp += wv * mv;
    }
    for (int off = 32; off > 0; off >>= 1) { bp += __shfl_xor(bp, off); gp += __shfl_xor(gp, off); }
    if (l == 0) { float* p = bg + (b * NH + h) * 2; p[0] = bp; p[1] = gp; }
  }
  __syncthreads();

  // ---- phase 2: z[h,c] = sum_s w[h,s]*sites[s,c] via MFMA, chunked over s ----
  f32x4 z0 = {0.f, 0.f, 0.f, 0.f}, z1 = {0.f, 0.f, 0.f, 0.f};
  int half = t >> 8, tc = t & 255;
  for (int chunk = 0; chunk < 4; ++chunk) {
    // stage transposed bf16 tile: St[c][s_local], s_local in [0,64)
    const float* Sp = sites + ((size_t)b * NS + chunk * 64) * ND + tc;
#pragma unroll
    for (int it = 0; it < 4; ++it) {
      int s8 = (half * 4 + it) * 8;
      bf8v vtmp;
#pragma unroll
      for (int j = 0; j < 8; ++j) vtmp[j] = f2bf(Sp[(size_t)(s8 + j) * ND]);
      *(bf8v*)&St[tc][s8] = vtmp;
    }
    __syncthreads();
#pragma unroll
    for (int kst = 0; kst < 2; ++kst) {
      int sg = chunk * 64 + kst * 32 + ksub * 8;   // global s for A (w rows)
      int sl0 = kst * 32 + ksub * 8;               // local s for B (St rows)
      float4 p0 = *(const float4*)&us[r16][sg];
      float4 p1 = *(const float4*)&us[r16][sg + 4];
      bf8v ah, al;
      split8(p0, p1, ah, al);
      bf8v b0 = *(const bf8v*)&St[(2 * w) * 16 + r16][sl0];
      bf8v b1 = *(const bf8v*)&St[(2 * w + 1) * 16 + r16][sl0];
      z0 = __builtin_amdgcn_mfma_f32_16x16x32_bf16(ah, b0, z0, 0, 0, 0);
      z0 = __builtin_amdgcn_mfma_f32_16x16x32_bf16(al, b0, z0, 0, 0, 0);
      z1 = __builtin_amdgcn_mfma_f32_16x16x32_bf16(ah, b1, z1, 0, 0, 0);
      z1 = __builtin_amdgcn_mfma_f32_16x16x32_bf16(al, b1, z1, 0, 0, 0);
    }
    __syncthreads();
  }
  if (ksub < 2) {
#pragma unroll
    for (int q = 0; q < 4; ++q) {
      int h = ksub * 4 + q;
      zbuf[((size_t)b * NH + h) * ND + 2 * w * 16 + r16] = z0[q];
      zbuf[((size_t)b * NH + h) * ND + (2 * w + 1) * 16 + r16] = z1[q];
    }
  }
}

// ---------- K6: z@Wv, residual, LN1, @Wo, LN2 ; constant 'a' output ----------
__global__ __launch_bounds__(256) void k_out(const float* __restrict__ zbuf,
                                             const float* __restrict__ bg,
                                             const float* __restrict__ q_ln,
                                             const float* __restrict__ Wv,
                                             const float* __restrict__ bv,
                                             const float* __restrict__ gv,
                                             const float* __restrict__ betv,
                                             const float* __restrict__ g1,
                                             const float* __restrict__ b1,
                                             const float* __restrict__ Wo,
                                             const float* __restrict__ bo,
                                             const float* __restrict__ g2,
                                             const float* __restrict__ b2,
                                             const float* __restrict__ beta_a,
                                             float* __restrict__ out) {
  int b = blockIdx.x, t = threadIdx.x;
  __shared__ float zs[8][257];
  __shared__ float y1s[2048];
  __shared__ float red[256];
  __shared__ float bets[8], gams[8];
  for (int i = 0; i < 8; ++i) zs[i][t] = zbuf[(size_t)(b * NH + i) * ND + t];
  if (t < 8) { const float* p = bg + (b * NH + t) * 2; bets[t] = p[0]; gams[t] = p[1]; }
  __syncthreads();
  float acc[8];
#pragma unroll
  for (int r = 0; r < 8; ++r) acc[r] = 0.f;
  for (int c = 0; c < 256; ++c) {
    const float* wrow = Wv + (size_t)c * NHD + t;
#pragma unroll
    for (int r = 0; r < 8; ++r) acc[r] = fmaf(zs[r][c], wrow[r * 256], acc[r]);
  }
  float s1 = 0.f, s2 = 0.f;
  float vv[8];
#pragma unroll
  for (int r = 0; r < 8; ++r) {
    int j = r * 256 + t;
    float av = gv[j] * (acc[r] + bv[j] * bets[r] - gams[r]) + betv[j];
    float o = av + q_ln[(size_t)b * NHD + j];
    vv[r] = o;
    s1 += o;
    s2 += o * o;
  }
  s1 = block_reduce_sum(s1, red, t);
  s2 = block_reduce_sum(s2, red, t);
  float m = s1 * (1.0f / NHD);
  float var = s2 * (1.0f / NHD) - m * m;
  float is = 1.0f / sqrtf(var + EPS);
#pragma unroll
  for (int r = 0; r < 8; ++r) {
    int j = r * 256 + t;
    y1s[j] = (vv[r] - m) * is * g1[j] + b1[j];
  }
  __syncthreads();
  float acc2 = bo[t];
  for (int jj = 0; jj < 2048; ++jj) acc2 = fmaf(y1s[jj], Wo[(size_t)jj * 256 + t], acc2);
  float q1 = block_reduce_sum(acc2, red, t);
  float q2 = block_reduce_sum(acc2 * acc2, red, t);
  float m2 = q1 * (1.0f / 256.0f);
  float v2 = q2 * (1.0f / 256.0f) - m2 * m2;
  float is2 = 1.0f / sqrtf(v2 + EPS);
  out[NB * NS + b * 256 + t] = (acc2 - m2) * is2 * g2[t] + b2[t];
  out[b * 256 + t] = beta_a[0];
}

extern "C" void kernel_launch(void* const* d_in, const int* in_sizes, int n_in,
                              void* d_out, int out_size, void* d_ws, size_t ws_size,
                              hipStream_t stream) {
  (void)in_sizes; (void)n_in; (void)out_size; (void)ws_size;
  const float* local = (const float*)d_in[0];
  const float* dist  = (const float*)d_in[1];
  const float* sites = (const float*)d_in[2];
  const int*   mask  = (const int*)d_in[3];
  const float* Wq   = (const float*)d_in[4];
  const float* bq   = (const float*)d_in[5];
  const float* gq   = (const float*)d_in[6];
  const float* betq = (const float*)d_in[7];
  const float* Wk   = (const float*)d_in[8];
  const float* bk   = (const float*)d_in[9];
  const float* gk   = (const float*)d_in[10];
  const float* betk = (const float*)d_in[11];
  const float* Wv   = (const float*)d_in[12];
  const float* bv   = (const float*)d_in[13];
  const float* gv   = (const float*)d_in[14];
  const float* betv = (const float*)d_in[15];
  const float* g1   = (const float*)d_in[16];
  const float* b1   = (const float*)d_in[17];
  const float* Wo   = (const float*)d_in[18];
  const float* bo   = (const float*)d_in[19];
  const float* g2   = (const float*)d_in[20];
  const float* b2   = (const float*)d_in[21];
  const float* beta_a = (const float*)d_in[25];
  float* out = (float*)d_out;

  float* ws = (float*)d_ws;
  float* MkP   = ws;                // 262144
  float* MvP   = MkP + 262144;      // 262144
  short* Mkb   = (short*)(MvP + 262144);   // 65536 shorts
  short* Mvb   = Mkb + 65536;              // 65536 shorts
  float* kmeta = (float*)(Mvb + 65536);    // 1024
  float* vmeta = kmeta + 1024;      // 1024
  float* q_ln  = vmeta + 1024;      // 262144
  float* wkeff = q_ln + 262144;     // 262144
  float* cbGT  = wkeff + 262144;    // 4096
  float* mk_arr = cbGT + 4096;      // 32768
  float* sk_arr = mk_arr + 32768;   // 32768
  float* mv_arr = sk_arr + 32768;   // 32768
  float* sv_arr = mv_arr + 32768;   // 32768
  float* zbuf  = sv_arr + 32768;    // 262144
  float* bg    = zbuf + 262144;     // 2048
  int*   mflag = (int*)(bg + 2048); // 16

  k_meta<<<dim3(256, 2), dim3(256), 0, stream>>>(Wk, bk, Wv, bv, kmeta, vmeta);
  k_aat<<<dim3(8, 8, 8), dim3(256), 0, stream>>>(Wk, Wv, MkP, MvP);
  k_aat_reduce<<<dim3(256, 2), dim3(256), 0, stream>>>(MkP, MvP, Mkb, Mvb);
  k_qln<<<dim3(128), dim3(256), 0, stream>>>(local, Wq, bq, gq, betq, q_ln);
  k_wkeff<<<dim3(8, 128), dim3(256), 0, stream>>>(q_ln, Wk, bk, gk, betk, wkeff, cbGT);
  k_maskflag<<<dim3(1), dim3(256), 0, stream>>>(mask, mflag);
  k_moments<<<dim3(256, 2), dim3(256), 0, stream>>>(dist, sites, Mkb, Mvb, kmeta, vmeta,
                                                    mk_arr, sk_arr, mv_arr, sv_arr);
  k_attn2<<<dim3(128), dim3(512), 0, stream>>>(dist, sites, mask, mflag, wkeff, cbGT,
                                               mk_arr, sk_arr, mv_arr, sv_arr, zbuf, bg);
  k_out<<<dim3(128), dim3(256), 0, stream>>>(zbuf, bg, q_ln, Wv, bv, gv, betv,
                                             g1, b1, Wo, bo, g2, b2, beta_a, out);
}

// Round 4
// 195.965 us; speedup vs baseline: 2.0007x; 1.3858x over previous
//
#include <hip/hip_runtime.h>

#define NB 128
#define NS 256
#define ND 256
#define NH 8
#define NHD 2048
static constexpr float EPS = 1e-5f;

typedef __attribute__((ext_vector_type(8))) short bf8v;
typedef __attribute__((ext_vector_type(4))) float f32x4;

__device__ __forceinline__ short f2bf(float f) {
  unsigned u = __float_as_uint(f);
  unsigned r = (u + 0x7fffu + ((u >> 16) & 1u)) >> 16;
  return (short)r;
}

__device__ __forceinline__ void split8(float4 a, float4 b, bf8v& hi, bf8v& lo) {
  float x[8] = {a.x, a.y, a.z, a.w, b.x, b.y, b.z, b.w};
  bf8v h, l;
#pragma unroll
  for (int i = 0; i < 8; ++i) {
    unsigned u = __float_as_uint(x[i]);
    unsigned hb = (u + 0x7fffu + ((u >> 16) & 1u)) >> 16;
    h[i] = (short)hb;
    float hf = __uint_as_float(hb << 16);
    l[i] = f2bf(x[i] - hf);
  }
  hi = h;
  lo = l;
}

// ---------- helpers ----------
__device__ __forceinline__ float block_reduce_sum(float v, float* red, int t) {
  __syncthreads();
  red[t] = v;
  __syncthreads();
  for (int off = 128; off > 0; off >>= 1) {
    if (t < off) red[t] += red[t + off];
    __syncthreads();
  }
  return red[0];
}

// ---------- K0: per-matrix meta ----------
__global__ __launch_bounds__(256) void k_meta(const float* __restrict__ Wk,
                                              const float* __restrict__ bk,
                                              const float* __restrict__ Wv,
                                              const float* __restrict__ bv,
                                              float* __restrict__ kmeta,
                                              float* __restrict__ vmeta) {
  int sel = blockIdx.y, c = blockIdx.x, t = threadIdx.x;
  const float* W = sel ? Wv : Wk;
  const float* bvec = sel ? bv : bk;
  float* meta = sel ? vmeta : kmeta;
  __shared__ float red[256];
  float s_w = 0.f, s_l = 0.f;
  const float* row = W + (size_t)c * NHD;
  for (int j = t; j < NHD; j += 256) { float w = row[j]; s_w += w; s_l += w * bvec[j]; }
  s_w = block_reduce_sum(s_w, red, t);
  s_l = block_reduce_sum(s_l, red, t);
  if (t == 0) { meta[c] = s_w * (1.0f / NHD); meta[256 + c] = s_l * (2.0f / NHD); }
  if (c == 0) {
    float s_b = 0.f, s_b2 = 0.f;
    for (int j = t; j < NHD; j += 256) { float bb = bvec[j]; s_b += bb; s_b2 += bb * bb; }
    s_b = block_reduce_sum(s_b, red, t);
    s_b2 = block_reduce_sum(s_b2, red, t);
    if (t == 0) { meta[512] = s_b * (1.0f / NHD); meta[513] = s_b2 * (1.0f / NHD); }
  }
}

// ---------- K2a: partial A*A^T over K-slices ----------
__global__ __launch_bounds__(256) void k_aat(const float* __restrict__ Wk,
                                             const float* __restrict__ Wv,
                                             float* __restrict__ MkP,
                                             float* __restrict__ MvP) {
  int bi = blockIdx.x, bj = blockIdx.y;
  int sel = blockIdx.z & 1, ks = blockIdx.z >> 1;
  const float* A = sel ? Wv : Wk;
  float* outP = (sel ? MvP : MkP) + ks * (256 * 256);
  int t = threadIdx.x;
  __shared__ float As[32][129];
  __shared__ float Bs[32][129];
  int ty = t >> 4, tx = t & 15;
  float a00 = 0.f, a01 = 0.f, a10 = 0.f, a11 = 0.f;
  for (int kc = 0; kc < 4; ++kc) {
    int k0 = ks * 512 + kc * 128;
    __syncthreads();
    for (int i = 0; i < 16; ++i) {
      int li = t + 256 * i;
      int r = li >> 7, cc = li & 127;
      As[r][cc] = A[(size_t)(bi * 32 + r) * NHD + k0 + cc];
      Bs[r][cc] = A[(size_t)(bj * 32 + r) * NHD + k0 + cc];
    }
    __syncthreads();
    for (int k = 0; k < 128; ++k) {
      float x0 = As[ty][k], x1 = As[ty + 16][k];
      float y0 = Bs[tx][k], y1 = Bs[tx + 16][k];
      a00 = fmaf(x0, y0, a00); a01 = fmaf(x0, y1, a01);
      a10 = fmaf(x1, y0, a10); a11 = fmaf(x1, y1, a11);
    }
  }
  int r0 = bi * 32 + ty, c0 = bj * 32 + tx;
  outP[r0 * 256 + c0] = a00;
  outP[r0 * 256 + c0 + 16] = a01;
  outP[(r0 + 16) * 256 + c0] = a10;
  outP[(r0 + 16) * 256 + c0 + 16] = a11;
}

// reduce partials -> bf16 M (row-major; M symmetric)
__global__ __launch_bounds__(256) void k_aat_reduce(const float* __restrict__ MkP,
                                                    const float* __restrict__ MvP,
                                                    short* __restrict__ Mkb,
                                                    short* __restrict__ Mvb) {
  int sel = blockIdx.y;
  const float* P = sel ? MvP : MkP;
  short* O = sel ? Mvb : Mkb;
  int idx = blockIdx.x * 256 + threadIdx.x;
  float s = (P[idx] + P[65536 + idx] + P[131072 + idx] + P[196608 + idx]) * (1.0f / NHD);
  O[idx] = f2bf(s);
}

// ---------- K3a: qraw = local @ Wq + bq (head-split) + LN partials ----------
__global__ __launch_bounds__(256) void k_q1(const float* __restrict__ local,
                                            const float* __restrict__ Wq,
                                            const float* __restrict__ bq,
                                            float* __restrict__ qraw,
                                            float* __restrict__ qpart) {
  int h = blockIdx.x, b = blockIdx.y, t = threadIdx.x;
  __shared__ float ls[256];
  __shared__ float red[256];
  ls[t] = local[b * ND + t];
  __syncthreads();
  int j = h * 256 + t;
  float a0 = 0.f, a1 = 0.f, a2 = 0.f, a3 = 0.f;
  const float* W = Wq + j;
#pragma unroll 4
  for (int c = 0; c < 256; c += 4) {
    a0 = fmaf(ls[c],     W[(size_t)c * NHD], a0);
    a1 = fmaf(ls[c + 1], W[(size_t)(c + 1) * NHD], a1);
    a2 = fmaf(ls[c + 2], W[(size_t)(c + 2) * NHD], a2);
    a3 = fmaf(ls[c + 3], W[(size_t)(c + 3) * NHD], a3);
  }
  float acc = (a0 + a1) + (a2 + a3) + bq[j];
  qraw[(size_t)b * NHD + j] = acc;
  float s1 = block_reduce_sum(acc, red, t);
  float s2 = block_reduce_sum(acc * acc, red, t);
  if (t == 0) { qpart[(b * 8 + h) * 2] = s1; qpart[(b * 8 + h) * 2 + 1] = s2; }
}

// ---------- K3b: apply LN -> q_ln ----------
__global__ __launch_bounds__(256) void k_q2(const float* __restrict__ qraw,
                                            const float* __restrict__ qpart,
                                            const float* __restrict__ gq,
                                            const float* __restrict__ betq,
                                            float* __restrict__ q_ln) {
  int b = blockIdx.x, t = threadIdx.x;
  float s1 = 0.f, s2 = 0.f;
#pragma unroll
  for (int i = 0; i < 8; ++i) { s1 += qpart[(b * 8 + i) * 2]; s2 += qpart[(b * 8 + i) * 2 + 1]; }
  float m = s1 * (1.0f / NHD);
  float var = s2 * (1.0f / NHD) - m * m;
  float is = 1.0f / sqrtf(var + EPS);
#pragma unroll
  for (int r = 0; r < 8; ++r) {
    int j = r * 256 + t;
    float v = qraw[(size_t)b * NHD + j];
    q_ln[(size_t)b * NHD + j] = (v - m) * is * gq[j] + betq[j];
  }
}

// ---------- K4: wkeff ----------
__global__ __launch_bounds__(256) void k_wkeff(const float* __restrict__ q_ln,
                                               const float* __restrict__ Wk,
                                               const float* __restrict__ bk,
                                               const float* __restrict__ gk,
                                               const float* __restrict__ betk,
                                               float* __restrict__ wkeff,
                                               float* __restrict__ cbGT) {
  int h = blockIdx.x, b = blockIdx.y, t = threadIdx.x;
  __shared__ float qg[256];
  __shared__ float red[256];
  int j = h * 256 + t;
  float q = q_ln[(size_t)b * NHD + j];
  float qgv = q * gk[j];
  qg[t] = qgv;
  float cb = block_reduce_sum(bk[j] * qgv, red, t);
  float G = block_reduce_sum(qgv, red, t);
  float T = block_reduce_sum(q * betk[j], red, t);
  float acc = 0.f;
  const float4* wr = (const float4*)(Wk + (size_t)t * NHD + h * 256);
#pragma unroll 4
  for (int d4 = 0; d4 < 64; ++d4) {
    float4 w = wr[d4];
    acc += w.x * qg[d4 * 4] + w.y * qg[d4 * 4 + 1] + w.z * qg[d4 * 4 + 2] + w.w * qg[d4 * 4 + 3];
  }
  wkeff[(size_t)(b * NH + h) * ND + t] = acc;
  if (t == 0) { float* p = cbGT + (b * NH + h) * 4; p[0] = cb; p[1] = G; p[2] = T; }
}

// ---------- mask-format detect (once) ----------
__global__ __launch_bounds__(256) void k_maskflag(const int* __restrict__ mask_i,
                                                  int* __restrict__ flag) {
  __shared__ int s;
  int t = threadIdx.x;
  if (t == 0) s = 0;
  __syncthreads();
  int any = 0;
  for (int i = t; i < 8192; i += 256) {
    unsigned v = (unsigned)mask_i[i];
    if (v > 1u) any = 1;
  }
  if (any) atomicOr(&s, 1);
  __syncthreads();
  if (t == 0) flag[0] = s;
}

// ---------- K5a (MFMA): LN moments via y = x^T M x ----------
__global__ __launch_bounds__(256) void k_moments(const float* __restrict__ dist,
                                                 const float* __restrict__ sites,
                                                 const short* __restrict__ Mkb,
                                                 const short* __restrict__ Mvb,
                                                 const float* __restrict__ kmeta,
                                                 const float* __restrict__ vmeta,
                                                 float* __restrict__ mk_arr,
                                                 float* __restrict__ sk_arr,
                                                 float* __restrict__ mv_arr,
                                                 float* __restrict__ sv_arr) {
  int sel = blockIdx.y;
  const float* X = sel ? sites : dist;
  const short* Mb = sel ? Mvb : Mkb;
  const float* meta = sel ? vmeta : kmeta;
  float* m_out = sel ? mv_arr : mk_arr;
  float* s_out = sel ? sv_arr : sk_arr;

  int t = threadIdx.x;
  int w = t >> 6;
  int l = t & 63;
  int r16 = l & 15;
  int ksub = l >> 4;

  __shared__ __align__(16) short Tb[4][2][16][40];

  size_t rowA = (size_t)blockIdx.x * 128 + w * 32;
  const float* xr0 = X + (rowA + r16) * 256;
  const float* xr1 = xr0 + 16 * 256;

  bf8v af0[8], af1[8];
  float pm0 = 0.f, pl0 = 0.f, pm1 = 0.f, pl1 = 0.f;
#pragma unroll
  for (int kc = 0; kc < 8; ++kc) {
    int c0 = kc * 32 + ksub * 8;
    float4 wa = *(const float4*)(meta + c0);
    float4 wb = *(const float4*)(meta + c0 + 4);
    float4 la = *(const float4*)(meta + 256 + c0);
    float4 lb = *(const float4*)(meta + 256 + c0 + 4);
    float4 x0a = *(const float4*)(xr0 + c0);
    float4 x0b = *(const float4*)(xr0 + c0 + 4);
    float4 x1a = *(const float4*)(xr1 + c0);
    float4 x1b = *(const float4*)(xr1 + c0 + 4);
    pm0 += x0a.x * wa.x + x0a.y * wa.y + x0a.z * wa.z + x0a.w * wa.w
         + x0b.x * wb.x + x0b.y * wb.y + x0b.z * wb.z + x0b.w * wb.w;
    pl0 += x0a.x * la.x + x0a.y * la.y + x0a.z * la.z + x0a.w * la.w
         + x0b.x * lb.x + x0b.y * lb.y + x0b.z * lb.z + x0b.w * lb.w;
    pm1 += x1a.x * wa.x + x1a.y * wa.y + x1a.z * wa.z + x1a.w * wa.w
         + x1b.x * wb.x + x1b.y * wb.y + x1b.z * wb.z + x1b.w * wb.w;
    pl1 += x1a.x * la.x + x1a.y * la.y + x1a.z * la.z + x1a.w * la.w
         + x1b.x * lb.x + x1b.y * lb.y + x1b.z * lb.z + x1b.w * lb.w;
    bf8v a0, a1;
    a0[0] = f2bf(x0a.x); a0[1] = f2bf(x0a.y); a0[2] = f2bf(x0a.z); a0[3] = f2bf(x0a.w);
    a0[4] = f2bf(x0b.x); a0[5] = f2bf(x0b.y); a0[6] = f2bf(x0b.z); a0[7] = f2bf(x0b.w);
    a1[0] = f2bf(x1a.x); a1[1] = f2bf(x1a.y); a1[2] = f2bf(x1a.z); a1[3] = f2bf(x1a.w);
    a1[4] = f2bf(x1b.x); a1[5] = f2bf(x1b.y); a1[6] = f2bf(x1b.z); a1[7] = f2bf(x1b.w);
    af0[kc] = a0;
    af1[kc] = a1;
  }
  pm0 += __shfl_xor(pm0, 16); pm0 += __shfl_xor(pm0, 32);
  pl0 += __shfl_xor(pl0, 16); pl0 += __shfl_xor(pl0, 32);
  pm1 += __shfl_xor(pm1, 16); pm1 += __shfl_xor(pm1, 32);
  pl1 += __shfl_xor(pl1, 16); pl1 += __shfl_xor(pl1, 32);

  f32x4 y0 = {0.f, 0.f, 0.f, 0.f}, y1 = {0.f, 0.f, 0.f, 0.f};

#pragma unroll
  for (int n = 0; n < 16; ++n) {
    bf8v bf[8];
#pragma unroll
    for (int kc = 0; kc < 8; ++kc)
      bf[kc] = *(const bf8v*)(Mb + ((size_t)(n * 16 + r16) << 8) + kc * 32 + ksub * 8);
    f32x4 ta = {0.f, 0.f, 0.f, 0.f}, tb = {0.f, 0.f, 0.f, 0.f};
#pragma unroll
    for (int kc = 0; kc < 8; ++kc) {
      ta = __builtin_amdgcn_mfma_f32_16x16x32_bf16(af0[kc], bf[kc], ta, 0, 0, 0);
      tb = __builtin_amdgcn_mfma_f32_16x16x32_bf16(af1[kc], bf[kc], tb, 0, 0, 0);
    }
#pragma unroll
    for (int q = 0; q < 4; ++q) {
      Tb[w][0][ksub * 4 + q][(n & 1) * 16 + r16] = f2bf(ta[q]);
      Tb[w][1][ksub * 4 + q][(n & 1) * 16 + r16] = f2bf(tb[q]);
    }
    if (n & 1) {
      bf8v a20 = *(const bf8v*)&Tb[w][0][r16][ksub * 8];
      bf8v a21 = *(const bf8v*)&Tb[w][1][r16][ksub * 8];
      y0 = __builtin_amdgcn_mfma_f32_16x16x32_bf16(a20, af0[n >> 1], y0, 0, 0, 0);
      y1 = __builtin_amdgcn_mfma_f32_16x16x32_bf16(a21, af1[n >> 1], y1, 0, 0, 0);
    }
  }

  int qs = r16 & 3;
  float yd0 = (qs == 0) ? y0[0] : (qs == 1) ? y0[1] : (qs == 2) ? y0[2] : y0[3];
  float yd1 = (qs == 0) ? y1[0] : (qs == 1) ? y1[1] : (qs == 2) ? y1[2] : y1[3];
  float bbar = meta[512], cc = meta[513];
  if (ksub == (r16 >> 2)) {
    float m0 = pm0 + bbar;
    float var0 = fmaxf(yd0 + (pl0 + cc) - m0 * m0, 0.0f) + EPS;
    m_out[rowA + r16] = m0;
    s_out[rowA + r16] = 1.0f / sqrtf(var0);
    float m1 = pm1 + bbar;
    float var1 = fmaxf(yd1 + (pl1 + cc) - m1 * m1, 0.0f) + EPS;
    m_out[rowA + 16 + r16] = m1;
    s_out[rowA + 16 + r16] = 1.0f / sqrtf(var1);
  }
}

// ---------- K5 (MFMA): fused scores + softmax + PV, one block per b ----------
__global__ __launch_bounds__(512) void k_attn2(const float* __restrict__ dist,
                                               const float* __restrict__ sites,
                                               const int* __restrict__ mask_i,
                                               const int* __restrict__ mflag,
                                               const float* __restrict__ wkeff,
                                               const float* __restrict__ cbGT,
                                               const float* __restrict__ mk_arr,
                                               const float* __restrict__ sk_arr,
                                               const float* __restrict__ mv_arr,
                                               const float* __restrict__ sv_arr,
                                               float* __restrict__ zbuf,
                                               float* __restrict__ bg) {
  int b = blockIdx.x, t = threadIdx.x;
  int w = t >> 6, l = t & 63, r16 = l & 15, ksub = l >> 4;

  __shared__ float us[16][260];
  __shared__ __align__(16) short St[256][72];

  for (int i = t; i < 8 * 260; i += 512) (&us[8][0])[i] = 0.f;

  const int mbytes = mflag[0];

  const float* xr0 = dist + ((size_t)b * NS + w * 32 + r16) * ND;
  const float* xr1 = xr0 + 16 * ND;
  const float* wkp = wkeff + ((size_t)b * NH + (r16 & 7)) * ND;
  f32x4 u0 = {0.f, 0.f, 0.f, 0.f}, u1 = {0.f, 0.f, 0.f, 0.f};
#pragma unroll 2
  for (int kc = 0; kc < 8; ++kc) {
    int c0 = kc * 32 + ksub * 8;
    float4 xa = *(const float4*)(xr0 + c0);
    float4 xb = *(const float4*)(xr0 + c0 + 4);
    float4 ya = *(const float4*)(xr1 + c0);
    float4 yb = *(const float4*)(xr1 + c0 + 4);
    float4 wa = {0.f, 0.f, 0.f, 0.f}, wb = {0.f, 0.f, 0.f, 0.f};
    if (r16 < 8) { wa = *(const float4*)(wkp + c0); wb = *(const float4*)(wkp + c0 + 4); }
    bf8v xh, xl, yh, yl, wh, wl;
    split8(xa, xb, xh, xl);
    split8(ya, yb, yh, yl);
    split8(wa, wb, wh, wl);
    u0 = __builtin_amdgcn_mfma_f32_16x16x32_bf16(xh, wh, u0, 0, 0, 0);
    u0 = __builtin_amdgcn_mfma_f32_16x16x32_bf16(xl, wh, u0, 0, 0, 0);
    u0 = __builtin_amdgcn_mfma_f32_16x16x32_bf16(xh, wl, u0, 0, 0, 0);
    u1 = __builtin_amdgcn_mfma_f32_16x16x32_bf16(yh, wh, u1, 0, 0, 0);
    u1 = __builtin_amdgcn_mfma_f32_16x16x32_bf16(yl, wh, u1, 0, 0, 0);
    u1 = __builtin_amdgcn_mfma_f32_16x16x32_bf16(yh, wl, u1, 0, 0, 0);
  }

  float cb = 0.f, G = 0.f, T = 0.f;
  if (r16 < 8) { const float* p = cbGT + (b * NH + r16) * 4; cb = p[0]; G = p[1]; T = p[2]; }
  const unsigned char* mask_b = (const unsigned char*)mask_i;
#pragma unroll
  for (int g = 0; g < 2; ++g) {
    f32x4 uu = g ? u1 : u0;
    int base = w * 32 + g * 16 + ksub * 4;
    float4 mk4 = *(const float4*)(mk_arr + b * NS + base);
    float4 sk4 = *(const float4*)(sk_arr + b * NS + base);
    int mm[4];
    if (mbytes) {
      mm[0] = mask_b[b * NS + base];     mm[1] = mask_b[b * NS + base + 1];
      mm[2] = mask_b[b * NS + base + 2]; mm[3] = mask_b[b * NS + base + 3];
    } else {
      mm[0] = mask_i[b * NS + base];     mm[1] = mask_i[b * NS + base + 1];
      mm[2] = mask_i[b * NS + base + 2]; mm[3] = mask_i[b * NS + base + 3];
    }
    const float* mkp = (const float*)&mk4;
    const float* skp = (const float*)&sk4;
#pragma unroll
    for (int q = 0; q < 4; ++q) {
      float u = ((uu[q] + cb - mkp[q] * G) * skp[q] + T) * 0.0625f;
      if (mm[q]) u = -1e30f;
      if (r16 < 8) us[r16][base + q] = u;
    }
  }
  __syncthreads();

  {
    int h = w;
    float v[4];
#pragma unroll
    for (int i = 0; i < 4; ++i) v[i] = us[h][l + 64 * i];
    float mx = fmaxf(fmaxf(v[0], v[1]), fmaxf(v[2], v[3]));
    for (int off = 32; off > 0; off >>= 1) mx = fmaxf(mx, __shfl_xor(mx, off));
    float sum = 0.f;
#pragma unroll
    for (int i = 0; i < 4; ++i) { v[i] = expf(v[i] - mx); sum += v[i]; }
    for (int off = 32; off > 0; off >>= 1) sum += __shfl_xor(sum, off);
    float inv = 1.0f / sum;
    float bp = 0.f, gp = 0.f;
#pragma unroll
    for (int i = 0; i < 4; ++i) {
      int s = l + 64 * i;
      float a = v[i] * inv;
      float sv = sv_arr[b * NS + s];
      float mv = mv_arr[b * NS + s];
      float wv = a * sv;
      us[h][s] = wv;
      bp += wv;
      gp += wv * mv;
    }
    for (int off = 32; off > 0; off >>= 1) { bp += __shfl_xor(bp, off); gp += __shfl_xor(gp, off); }
    if (l == 0) { float* p = bg + (b * NH + h) * 2; p[0] = bp; p[1] = gp; }
  }
  __syncthreads();

  f32x4 z0 = {0.f, 0.f, 0.f, 0.f}, z1 = {0.f, 0.f, 0.f, 0.f};
  int half = t >> 8, tc = t & 255;
  for (int chunk = 0; chunk < 4; ++chunk) {
    const float* Sp = sites + ((size_t)b * NS + chunk * 64) * ND + tc;
#pragma unroll
    for (int it = 0; it < 4; ++it) {
      int s8 = (half * 4 + it) * 8;
      bf8v vtmp;
#pragma unroll
      for (int j = 0; j < 8; ++j) vtmp[j] = f2bf(Sp[(size_t)(s8 + j) * ND]);
      *(bf8v*)&St[tc][s8] = vtmp;
    }
    __syncthreads();
#pragma unroll
    for (int kst = 0; kst < 2; ++kst) {
      int sg = chunk * 64 + kst * 32 + ksub * 8;
      int sl0 = kst * 32 + ksub * 8;
      float4 p0 = *(const float4*)&us[r16][sg];
      float4 p1 = *(const float4*)&us[r16][sg + 4];
      bf8v ah, al;
      split8(p0, p1, ah, al);
      bf8v b0 = *(const bf8v*)&St[(2 * w) * 16 + r16][sl0];
      bf8v b1 = *(const bf8v*)&St[(2 * w + 1) * 16 + r16][sl0];
      z0 = __builtin_amdgcn_mfma_f32_16x16x32_bf16(ah, b0, z0, 0, 0, 0);
      z0 = __builtin_amdgcn_mfma_f32_16x16x32_bf16(al, b0, z0, 0, 0, 0);
      z1 = __builtin_amdgcn_mfma_f32_16x16x32_bf16(ah, b1, z1, 0, 0, 0);
      z1 = __builtin_amdgcn_mfma_f32_16x16x32_bf16(al, b1, z1, 0, 0, 0);
    }
    __syncthreads();
  }
  if (ksub < 2) {
#pragma unroll
    for (int q = 0; q < 4; ++q) {
      int h = ksub * 4 + q;
      zbuf[((size_t)b * NH + h) * ND + 2 * w * 16 + r16] = z0[q];
      zbuf[((size_t)b * NH + h) * ND + (2 * w + 1) * 16 + r16] = z1[q];
    }
  }
}

// ---------- K6a: o = z@Wv + corrections + residual, LN1 partials (head-split) ----------
__global__ __launch_bounds__(256) void k_o1(const float* __restrict__ zbuf,
                                            const float* __restrict__ bg,
                                            const float* __restrict__ q_ln,
                                            const float* __restrict__ Wv,
                                            const float* __restrict__ bv,
                                            const float* __restrict__ gv,
                                            const float* __restrict__ betv,
                                            float* __restrict__ o_buf,
                                            float* __restrict__ part1) {
  int h = blockIdx.x, b = blockIdx.y, t = threadIdx.x;
  __shared__ float zs[256];
  __shared__ float red[256];
  zs[t] = zbuf[((size_t)b * NH + h) * ND + t];
  __syncthreads();
  float bets = bg[(b * NH + h) * 2], gams = bg[(b * NH + h) * 2 + 1];
  int j = h * 256 + t;
  float a0 = 0.f, a1 = 0.f, a2 = 0.f, a3 = 0.f;
  const float* W = Wv + j;
#pragma unroll 4
  for (int c = 0; c < 256; c += 4) {
    a0 = fmaf(zs[c],     W[(size_t)c * NHD], a0);
    a1 = fmaf(zs[c + 1], W[(size_t)(c + 1) * NHD], a1);
    a2 = fmaf(zs[c + 2], W[(size_t)(c + 2) * NHD], a2);
    a3 = fmaf(zs[c + 3], W[(size_t)(c + 3) * NHD], a3);
  }
  float acc = (a0 + a1) + (a2 + a3);
  float o = gv[j] * (acc + bv[j] * bets - gams) + betv[j] + q_ln[(size_t)b * NHD + j];
  o_buf[(size_t)b * NHD + j] = o;
  float s1 = block_reduce_sum(o, red, t);
  float s2 = block_reduce_sum(o * o, red, t);
  if (t == 0) { part1[(b * 8 + h) * 2] = s1; part1[(b * 8 + h) * 2 + 1] = s2; }
}

// ---------- K6b: y1 = LN1(o); split-K partials of y1@Wo ----------
__global__ __launch_bounds__(256) void k_o2(const float* __restrict__ o_buf,
                                            const float* __restrict__ part1,
                                            const float* __restrict__ g1,
                                            const float* __restrict__ b1,
                                            const float* __restrict__ Wo,
                                            float* __restrict__ part2) {
  int ks = blockIdx.x, b = blockIdx.y, t = threadIdx.x;
  __shared__ float y1s[256];
  float s1 = 0.f, s2 = 0.f;
#pragma unroll
  for (int i = 0; i < 8; ++i) { s1 += part1[(b * 8 + i) * 2]; s2 += part1[(b * 8 + i) * 2 + 1]; }
  float m = s1 * (1.0f / NHD);
  float var = s2 * (1.0f / NHD) - m * m;
  float is = 1.0f / sqrtf(var + EPS);
  int jj = ks * 256 + t;
  y1s[t] = (o_buf[(size_t)b * NHD + jj] - m) * is * g1[jj] + b1[jj];
  __syncthreads();
  float a0 = 0.f, a1 = 0.f, a2 = 0.f, a3 = 0.f;
  const float* W = Wo + (size_t)ks * 256 * 256 + t;
#pragma unroll 4
  for (int i = 0; i < 256; i += 4) {
    a0 = fmaf(y1s[i],     W[(size_t)i * 256], a0);
    a1 = fmaf(y1s[i + 1], W[(size_t)(i + 1) * 256], a1);
    a2 = fmaf(y1s[i + 2], W[(size_t)(i + 2) * 256], a2);
    a3 = fmaf(y1s[i + 3], W[(size_t)(i + 3) * 256], a3);
  }
  part2[((size_t)ks * NB + b) * 256 + t] = (a0 + a1) + (a2 + a3);
}

// ---------- K6c: reduce split-K, bias, LN2, write outputs ----------
__global__ __launch_bounds__(256) void k_o3(const float* __restrict__ part2,
                                            const float* __restrict__ bo,
                                            const float* __restrict__ g2,
                                            const float* __restrict__ b2,
                                            const float* __restrict__ beta_a,
                                            float* __restrict__ out) {
  int b = blockIdx.x, t = threadIdx.x;
  __shared__ float red[256];
  float acc = bo[t];
#pragma unroll
  for (int ks = 0; ks < 8; ++ks) acc += part2[((size_t)ks * NB + b) * 256 + t];
  float q1 = block_reduce_sum(acc, red, t);
  float q2 = block_reduce_sum(acc * acc, red, t);
  float m2 = q1 * (1.0f / 256.0f);
  float v2 = q2 * (1.0f / 256.0f) - m2 * m2;
  float is2 = 1.0f / sqrtf(v2 + EPS);
  out[NB * NS + b * 256 + t] = (acc - m2) * is2 * g2[t] + b2[t];
  out[b * 256 + t] = beta_a[0];
}

extern "C" void kernel_launch(void* const* d_in, const int* in_sizes, int n_in,
                              void* d_out, int out_size, void* d_ws, size_t ws_size,
                              hipStream_t stream) {
  (void)in_sizes; (void)n_in; (void)out_size; (void)ws_size;
  const float* local = (const float*)d_in[0];
  const float* dist  = (const float*)d_in[1];
  const float* sites = (const float*)d_in[2];
  const int*   mask  = (const int*)d_in[3];
  const float* Wq   = (const float*)d_in[4];
  const float* bq   = (const float*)d_in[5];
  const float* gq   = (const float*)d_in[6];
  const float* betq = (const float*)d_in[7];
  const float* Wk   = (const float*)d_in[8];
  const float* bk   = (const float*)d_in[9];
  const float* gk   = (const float*)d_in[10];
  const float* betk = (const float*)d_in[11];
  const float* Wv   = (const float*)d_in[12];
  const float* bv   = (const float*)d_in[13];
  const float* gv   = (const float*)d_in[14];
  const float* betv = (const float*)d_in[15];
  const float* g1   = (const float*)d_in[16];
  const float* b1   = (const float*)d_in[17];
  const float* Wo   = (const float*)d_in[18];
  const float* bo   = (const float*)d_in[19];
  const float* g2   = (const float*)d_in[20];
  const float* b2   = (const float*)d_in[21];
  const float* beta_a = (const float*)d_in[25];
  float* out = (float*)d_out;

  float* ws = (float*)d_ws;
  float* MkP   = ws;                // 262144 (later aliased: qraw, then o_buf)
  float* MvP   = MkP + 262144;      // 262144 (later aliased: part2)
  short* Mkb   = (short*)(MvP + 262144);   // 65536 shorts
  short* Mvb   = Mkb + 65536;              // 65536 shorts
  float* kmeta = (float*)(Mvb + 65536);    // 1024
  float* vmeta = kmeta + 1024;      // 1024
  float* q_ln  = vmeta + 1024;      // 262144
  float* wkeff = q_ln + 262144;     // 262144
  float* cbGT  = wkeff + 262144;    // 4096
  float* mk_arr = cbGT + 4096;      // 32768
  float* sk_arr = mk_arr + 32768;   // 32768
  float* mv_arr = sk_arr + 32768;   // 32768
  float* sv_arr = mv_arr + 32768;   // 32768
  float* zbuf  = sv_arr + 32768;    // 262144
  float* bg    = zbuf + 262144;     // 2048
  int*   mflag = (int*)(bg + 2048); // 16 ints
  float* part1 = (float*)(mflag + 16); // 2048
  float* qpart = part1 + 2048;      // 2048

  float* qraw  = MkP;   // dead after k_aat_reduce; live k_q1..k_q2
  float* o_buf = MkP;   // live k_o1..k_o2 (qraw dead by then)
  float* part2 = MvP;   // live k_o2..k_o3

  k_meta<<<dim3(256, 2), dim3(256), 0, stream>>>(Wk, bk, Wv, bv, kmeta, vmeta);
  k_aat<<<dim3(8, 8, 8), dim3(256), 0, stream>>>(Wk, Wv, MkP, MvP);
  k_aat_reduce<<<dim3(256, 2), dim3(256), 0, stream>>>(MkP, MvP, Mkb, Mvb);
  k_q1<<<dim3(8, 128), dim3(256), 0, stream>>>(local, Wq, bq, qraw, qpart);
  k_q2<<<dim3(128), dim3(256), 0, stream>>>(qraw, qpart, gq, betq, q_ln);
  k_wkeff<<<dim3(8, 128), dim3(256), 0, stream>>>(q_ln, Wk, bk, gk, betk, wkeff, cbGT);
  k_maskflag<<<dim3(1), dim3(256), 0, stream>>>(mask, mflag);
  k_moments<<<dim3(256, 2), dim3(256), 0, stream>>>(dist, sites, Mkb, Mvb, kmeta, vmeta,
                                                    mk_arr, sk_arr, mv_arr, sv_arr);
  k_attn2<<<dim3(128), dim3(512), 0, stream>>>(dist, sites, mask, mflag, wkeff, cbGT,
                                               mk_arr, sk_arr, mv_arr, sv_arr, zbuf, bg);
  k_o1<<<dim3(8, 128), dim3(256), 0, stream>>>(zbuf, bg, q_ln, Wv, bv, gv, betv, o_buf, part1);
  k_o2<<<dim3(8, 128), dim3(256), 0, stream>>>(o_buf, part1, g1, b1, Wo, part2);
  k_o3<<<dim3(128), dim3(256), 0, stream>>>(part2, bo, g2, b2, beta_a, out);
}